// Round 13
// baseline (1129.590 us; speedup 1.0000x reference)
//
#include <hip/hip_runtime.h>
#include <math.h>

#define N_NODES 20000
#define NHID    256
#define NOUT    128
#define HDIM    128
#define NHID_E  256
#define T_SNAP  16
#define E_EDGES 320000
#define EP_EDGES 100000
#define BN_EPS  1e-5f

#define BROWS 128                    // rows per bucket
#define NBUCK 157                    // ceil(N_NODES / BROWS)
#define BCAP  4096                   // staging capacity per bucket
#define P1CHUNK 2048                 // edges per k_p1 block (25KB LDS -> 6 blk/CU)

typedef unsigned short u16;
typedef __attribute__((ext_vector_type(8))) short bf16x8;
typedef __attribute__((ext_vector_type(8))) unsigned short u16x8;
typedef __attribute__((ext_vector_type(4))) float f32x4;

__device__ __forceinline__ u16 f2b(float f) {
    unsigned u = __float_as_uint(f);
    u += 0x7FFFu + ((u >> 16) & 1u);
    return (u16)(u >> 16);
}
__device__ __forceinline__ float b2f(u16 s) { return __uint_as_float(((unsigned)s) << 16); }

// ---- fast transcendentals (v_exp_f32 / v_rcp_f32), guarded ----
__device__ __forceinline__ float fexp2(float x) {
#if __has_builtin(__builtin_amdgcn_exp2f)
    return __builtin_amdgcn_exp2f(x);
#else
    return exp2f(x);
#endif
}
__device__ __forceinline__ float frcp(float x) {
#if __has_builtin(__builtin_amdgcn_rcpf)
    return __builtin_amdgcn_rcpf(x);
#else
    return 1.f / x;
#endif
}
__device__ __forceinline__ float fsig(float x) {
    return frcp(1.f + fexp2(x * -1.4426950408889634f));
}
__device__ __forceinline__ float ftanh(float x) {
    float t = fexp2(x * 2.8853900817779268f);
    return 1.f - 2.f * frcp(t + 1.f);
}

// ---- bf16 dot2 path (guarded; falls back to shl+fma if builtin absent) ----
#if __has_builtin(__builtin_amdgcn_fdot2_f32_bf16)
#define HAVE_DOT2 1
typedef __attribute__((ext_vector_type(2))) __bf16 bf2v;
__device__ __forceinline__ float dot2b(unsigned x, unsigned v, float acc) {
    return __builtin_amdgcn_fdot2_f32_bf16(
        __builtin_bit_cast(bf2v, x), __builtin_bit_cast(bf2v, v), acc, false);
}
__device__ __forceinline__ unsigned pack_lo(unsigned a, unsigned b) {
#if __has_builtin(__builtin_amdgcn_perm)
    return __builtin_amdgcn_perm(a, b, 0x01000504u);   // (a.e0 | b.e0<<16)
#else
    return (a & 0xFFFFu) | (b << 16);
#endif
}
__device__ __forceinline__ unsigned pack_hi(unsigned a, unsigned b) {
#if __has_builtin(__builtin_amdgcn_perm)
    return __builtin_amdgcn_perm(a, b, 0x03020706u);   // (a.e1 | b.e1<<16)
#else
    return (a >> 16) | (b & 0xFFFF0000u);
#endif
}
#else
#define HAVE_DOT2 0
#endif

// ---------------------------------------------------------------------------
// CSR build v2, phase 1: block-local counting sort by bucket, append runs.
// ---------------------------------------------------------------------------
__global__ __launch_bounds__(256) void k_p1(const int* __restrict__ rows,
        const int* __restrict__ cols, const float* __restrict__ vals,
        int* __restrict__ bcnt, uint2* __restrict__ staging,
        uint4* __restrict__ ovf, int* __restrict__ ovf_cnt) {
    int t = blockIdx.y;
    int base = blockIdx.x * P1CHUNK;
    int tid = threadIdx.x;
    __shared__ int hist[256], sc[256], excl[256], cursor[256], gbase[256];
    __shared__ uint2 ebuf[P1CHUNK];
    __shared__ u16 ebuck[P1CHUNK];
    hist[tid] = 0;
    __syncthreads();
    const int*   rt = rows + (size_t)t * E_EDGES;
    const int*   ct = cols + (size_t)t * E_EDGES;
    const float* vt = vals + (size_t)t * E_EDGES;
    #pragma unroll
    for (int k = 0; k < P1CHUNK / 256; ++k) {
        int i = base + k * 256 + tid;
        if (i < E_EDGES) atomicAdd(&hist[rt[i] >> 7], 1);
    }
    __syncthreads();
    sc[tid] = hist[tid];
    __syncthreads();
    for (int off = 1; off < 256; off <<= 1) {
        int add = (tid >= off) ? sc[tid - off] : 0;
        __syncthreads();
        sc[tid] += add;
        __syncthreads();
    }
    excl[tid]   = sc[tid] - hist[tid];
    cursor[tid] = sc[tid] - hist[tid];
    __syncthreads();
    #pragma unroll
    for (int k = 0; k < P1CHUNK / 256; ++k) {
        int i = base + k * 256 + tid;
        if (i < E_EDGES) {
            int r = rt[i];
            int b = r >> 7;
            int s = atomicAdd(&cursor[b], 1);
            uint2 e;
            e.x = (unsigned)ct[i] | ((unsigned)(r & 127) << 15);
            e.y = __float_as_uint(vt[i]);
            ebuf[s]  = e;
            ebuck[s] = (u16)b;
        }
    }
    __syncthreads();
    if (hist[tid] > 0) gbase[tid] = atomicAdd(&bcnt[t * NBUCK + tid], hist[tid]);
    __syncthreads();
    int nvalid = min(P1CHUNK, E_EDGES - base);
    for (int s = tid; s < nvalid; s += 256) {
        int b = ebuck[s];
        int g = gbase[b] + (s - excl[b]);
        if (g < BCAP) {
            staging[((size_t)t * NBUCK + b) * BCAP + g] = ebuf[s];
        } else {
            int o = atomicAdd(ovf_cnt, 1);
            uint4 e4; e4.x = (unsigned)(t * NBUCK + b); e4.y = ebuf[s].x; e4.z = ebuf[s].y; e4.w = 0;
            ovf[o] = e4;
        }
    }
}

// phase 2a: exclusive scan of all bucket counts (2512 values), one block
__global__ void k_bscan(const int* __restrict__ bcnt, int* __restrict__ bbase,
                        int* __restrict__ row_ptr) {
    __shared__ int sh[256];
    __shared__ int carry;
    int tid = threadIdx.x;
    if (tid == 0) carry = 0;
    __syncthreads();
    for (int b0 = 0; b0 < T_SNAP * NBUCK; b0 += 256) {
        int i = b0 + tid;
        int v = (i < T_SNAP * NBUCK) ? bcnt[i] : 0;
        sh[tid] = v;
        __syncthreads();
        for (int off = 1; off < 256; off <<= 1) {
            int add = (tid >= off) ? sh[tid - off] : 0;
            __syncthreads();
            sh[tid] += add;
            __syncthreads();
        }
        if (i < T_SNAP * NBUCK) bbase[i] = carry + sh[tid] - v;
        __syncthreads();
        if (tid == 255) carry += sh[255];
        __syncthreads();
    }
    if (tid < T_SNAP) row_ptr[tid * (N_NODES + 1) + N_NODES] = E_EDGES;
}

// phase 2b: per-bucket row sort -> row_ptr + final colval
__global__ __launch_bounds__(256) void k_p2(const int* __restrict__ bcnt,
        const int* __restrict__ bbase, const uint2* __restrict__ staging,
        const uint4* __restrict__ ovf, const int* __restrict__ ovf_cnt,
        uint2* __restrict__ colval, int* __restrict__ row_ptr) {
    int b = blockIdx.x, t = blockIdx.y, tid = threadIdx.x;
    int idx = t * NBUCK + b;
    int cnt = bcnt[idx];
    int gb  = bbase[idx];
    __shared__ int hist[BROWS], cursor[BROWS], sc[BROWS];
    if (tid < BROWS) hist[tid] = 0;
    __syncthreads();
    int staged = min(cnt, BCAP);
    const uint2* st = staging + (size_t)idx * BCAP;
    for (int s = tid; s < staged; s += 256)
        atomicAdd(&hist[st[s].x >> 15], 1);
    int nov = (cnt > staged) ? *ovf_cnt : 0;
    for (int o = tid; o < nov; o += 256) {
        uint4 e = ovf[o];
        if ((int)e.x == idx) atomicAdd(&hist[(e.y >> 15) & 127], 1);
    }
    __syncthreads();
    if (tid < BROWS) sc[tid] = hist[tid];
    __syncthreads();
    for (int off = 1; off < BROWS; off <<= 1) {
        int add = (tid < BROWS && tid >= off) ? sc[tid - off] : 0;
        __syncthreads();
        if (tid < BROWS) sc[tid] += add;
        __syncthreads();
    }
    if (tid < BROWS) {
        int ex = sc[tid] - hist[tid];
        cursor[tid] = ex;
        int row = b * BROWS + tid;
        if (row < N_NODES)
            row_ptr[t * (N_NODES + 1) + row] = gb - t * E_EDGES + ex;
    }
    __syncthreads();
    for (int s = tid; s < staged; s += 256) {
        uint2 e = st[s];
        int rl = e.x >> 15;
        int pos = atomicAdd(&cursor[rl], 1);
        uint2 o2; o2.x = e.x & 0x7FFF; o2.y = e.y;
        colval[(size_t)gb + pos] = o2;
    }
    for (int o = tid; o < nov; o += 256) {
        uint4 e = ovf[o];
        if ((int)e.x == idx) {
            int rl = (e.y >> 15) & 127;
            int pos = atomicAdd(&cursor[rl], 1);
            uint2 o2; o2.x = e.y & 0x7FFF; o2.y = e.z;
            colval[(size_t)gb + pos] = o2;
        }
    }
}

// ---------------------------------------------------------------------------
// Conversions / weight builders
// ---------------------------------------------------------------------------
__global__ void k_cvt(const float* __restrict__ in, u16* __restrict__ out, int n4) {
    int i = blockIdx.x * 256 + threadIdx.x;
    if (i < n4) {
        float4 v = ((const float4*)in)[i];
        ushort4 o;
        o.x = f2b(v.x); o.y = f2b(v.y); o.z = f2b(v.z); o.w = f2b(v.w);
        ((ushort4*)out)[i] = o;
    }
}

__global__ void k_tcvt(const float* __restrict__ in, u16* __restrict__ out, int Kr, int Nc) {
    int i = blockIdx.x * 256 + threadIdx.x;
    if (i < Kr * Nc) {
        int k = i / Nc, n = i - k * Nc;
        out[(size_t)n * Kr + k] = f2b(in[i]);
    }
}

// 512-col interleave over concat(x,h)
__global__ void k_build_bg(const float* __restrict__ Wih, const float* __restrict__ Whh,
                           u16* __restrict__ Bg) {
    int i = blockIdx.x * 256 + threadIdx.x;
    if (i >= 512 * 256) return;
    int rr = i >> 8, k = i & 255;
    int c = rr >> 4, u = rr & 15, g = c & 3, jj = ((c >> 2) << 4) + u;
    float v;
    if (g == 0)      v = (k < 128) ? Wih[(size_t)jj * 128 + k]         : Whh[(size_t)jj * 128 + k - 128];
    else if (g == 1) v = (k < 128) ? Wih[(size_t)(128 + jj) * 128 + k] : Whh[(size_t)(128 + jj) * 128 + k - 128];
    else if (g == 2) v = (k < 128) ? Wih[(size_t)(256 + jj) * 128 + k] : 0.f;
    else             v = (k < 128) ? 0.f : Whh[(size_t)(256 + jj) * 128 + k - 128];
    Bg[i] = f2b(v);
}

__global__ void k_build_bgb(const float* __restrict__ bih, const float* __restrict__ bhh,
                            float* __restrict__ bgb) {
    int rr = blockIdx.x * 256 + threadIdx.x;
    if (rr >= 512) return;
    int c = rr >> 4, u = rr & 15, g = c & 3, jj = ((c >> 2) << 4) + u;
    float v;
    if (g == 0)      v = bih[jj] + bhh[jj];
    else if (g == 1) v = bih[128 + jj] + bhh[128 + jj];
    else if (g == 2) v = bih[256 + jj];
    else             v = bhh[256 + jj];
    bgb[rr] = v;
}

// ---------------------------------------------------------------------------
// SpMM layer0 (D=256): one row per wave, half-wave per edge stream, 2 streams
// (r7 version — at the random-gather memory-path roofline).
// ---------------------------------------------------------------------------
template<bool RELU>
__global__ __launch_bounds__(256) void k_spmm0(
        const int* __restrict__ rp_all, const uint2* __restrict__ cv_all,
        int t0, const u16* __restrict__ X,
        const float* __restrict__ bias, u16* __restrict__ Out) {
    int lane = threadIdx.x & 63;
    int row = blockIdx.x * 4 + (threadIdx.x >> 6);
    int tl = blockIdx.y, t = t0 + tl;
    const int*   rp = rp_all + (size_t)t * (N_NODES + 1);
    const uint2* cv = cv_all + (size_t)t * E_EDGES;
    int hw = lane >> 5, l = lane & 31;
    int s = rp[row], e = rp[row + 1];
    int k = s + hw;
    uint2 a0 = make_uint2(0u, 0u), a1 = make_uint2(0u, 0u);
    if (k < e)     a0 = cv[k];
    if (k + 2 < e) a1 = cv[k + 2];
#if HAVE_DOT2
    float acc[8] = {};
    for (; k < e; k += 4) {
        uint2 c0 = a0, c1 = a1;
        bool ok1 = (k + 2) < e;
        int e1 = e - 1;
        a0 = cv[min(k + 4, e1)];
        a1 = cv[min(k + 6, e1)];
        unsigned col1 = ok1 ? c1.x : c0.x;
        float va1f = ok1 ? __uint_as_float(c1.y) : 0.f;
        unsigned vv = (unsigned)f2b(__uint_as_float(c0.y)) | ((unsigned)f2b(va1f) << 16);
        uint4 x0 = *(const uint4*)(X + (size_t)c0.x * NHID + l * 8);
        uint4 x1 = *(const uint4*)(X + (size_t)col1 * NHID + l * 8);
        acc[0] = dot2b(pack_lo(x0.x, x1.x), vv, acc[0]);
        acc[1] = dot2b(pack_hi(x0.x, x1.x), vv, acc[1]);
        acc[2] = dot2b(pack_lo(x0.y, x1.y), vv, acc[2]);
        acc[3] = dot2b(pack_hi(x0.y, x1.y), vv, acc[3]);
        acc[4] = dot2b(pack_lo(x0.z, x1.z), vv, acc[4]);
        acc[5] = dot2b(pack_hi(x0.z, x1.z), vv, acc[5]);
        acc[6] = dot2b(pack_lo(x0.w, x1.w), vv, acc[6]);
        acc[7] = dot2b(pack_hi(x0.w, x1.w), vv, acc[7]);
    }
    #pragma unroll
    for (int i = 0; i < 8; ++i) {
        float v = acc[i];
        v += __shfl_xor(v, 32);
        v += bias[l * 8 + i];
        acc[i] = RELU ? fmaxf(v, 0.f) : v;
    }
    float* accw = acc;
#else
    float acc0[8] = {}, acc1[8] = {};
    for (; k < e; k += 4) {
        uint2 c0 = a0, c1 = a1;
        bool ok1 = (k + 2) < e;
        int e1 = e - 1;
        a0 = cv[min(k + 4, e1)];
        a1 = cv[min(k + 6, e1)];
        float va0 = __uint_as_float(c0.y);
        float va1 = ok1 ? __uint_as_float(c1.y) : 0.f;
        unsigned col1 = ok1 ? c1.x : c0.x;
        u16x8 x0 = *(const u16x8*)(X + (size_t)c0.x * NHID + l * 8);
        u16x8 x1 = *(const u16x8*)(X + (size_t)col1 * NHID + l * 8);
        #pragma unroll
        for (int i = 0; i < 8; ++i) {
            acc0[i] = fmaf(va0, b2f(x0[i]), acc0[i]);
            acc1[i] = fmaf(va1, b2f(x1[i]), acc1[i]);
        }
    }
    #pragma unroll
    for (int i = 0; i < 8; ++i) {
        float v = acc0[i] + acc1[i];
        v += __shfl_xor(v, 32);
        v += bias[l * 8 + i];
        acc0[i] = RELU ? fmaxf(v, 0.f) : v;
    }
    float* accw = acc0;
#endif
    if (hw == 0) {
        u16x8 o;
        #pragma unroll
        for (int i = 0; i < 8; ++i) o[i] = f2b(accw[i]);
        *(u16x8*)(Out + ((size_t)tl * N_NODES + row) * NHID + l * 8) = o;
    }
}

// ---------------------------------------------------------------------------
// SpMM layer1 (D=128): quarter-wave per edge stream, 2 streams (r7 version).
// ---------------------------------------------------------------------------
template<bool RELU>
__global__ __launch_bounds__(256) void k_spmm1(
        const int* __restrict__ rp_all, const uint2* __restrict__ cv_all,
        int t0, const u16* __restrict__ X, size_t xtstride,
        const float* __restrict__ bias, u16* __restrict__ Out) {
    int lane = threadIdx.x & 63;
    int row = blockIdx.x * 4 + (threadIdx.x >> 6);
    int tl = blockIdx.y, t = t0 + tl;
    const int*   rp = rp_all + (size_t)t * (N_NODES + 1);
    const uint2* cv = cv_all + (size_t)t * E_EDGES;
    const u16*   Xt = X + xtstride * tl;
    int qw = lane >> 4, l = lane & 15;
    int s = rp[row], e = rp[row + 1];
    int k = s + qw;
    uint2 a0 = make_uint2(0u, 0u), a1 = make_uint2(0u, 0u);
    if (k < e)     a0 = cv[k];
    if (k + 4 < e) a1 = cv[k + 4];
#if HAVE_DOT2
    float acc[8] = {};
    for (; k < e; k += 8) {
        uint2 c0 = a0, c1 = a1;
        bool ok1 = (k + 4) < e;
        int e1 = e - 1;
        a0 = cv[min(k + 8, e1)];
        a1 = cv[min(k + 12, e1)];
        unsigned col1 = ok1 ? c1.x : c0.x;
        float va1f = ok1 ? __uint_as_float(c1.y) : 0.f;
        unsigned vv = (unsigned)f2b(__uint_as_float(c0.y)) | ((unsigned)f2b(va1f) << 16);
        uint4 x0 = *(const uint4*)(Xt + (size_t)c0.x * NOUT + l * 8);
        uint4 x1 = *(const uint4*)(Xt + (size_t)col1 * NOUT + l * 8);
        acc[0] = dot2b(pack_lo(x0.x, x1.x), vv, acc[0]);
        acc[1] = dot2b(pack_hi(x0.x, x1.x), vv, acc[1]);
        acc[2] = dot2b(pack_lo(x0.y, x1.y), vv, acc[2]);
        acc[3] = dot2b(pack_hi(x0.y, x1.y), vv, acc[3]);
        acc[4] = dot2b(pack_lo(x0.z, x1.z), vv, acc[4]);
        acc[5] = dot2b(pack_hi(x0.z, x1.z), vv, acc[5]);
        acc[6] = dot2b(pack_lo(x0.w, x1.w), vv, acc[6]);
        acc[7] = dot2b(pack_hi(x0.w, x1.w), vv, acc[7]);
    }
    #pragma unroll
    for (int i = 0; i < 8; ++i) {
        float v = acc[i];
        v += __shfl_xor(v, 32);
        v += __shfl_xor(v, 16);
        v += bias[l * 8 + i];
        acc[i] = RELU ? fmaxf(v, 0.f) : v;
    }
    float* accw = acc;
#else
    float acc0[8] = {}, acc1[8] = {};
    for (; k < e; k += 8) {
        uint2 c0 = a0, c1 = a1;
        bool ok1 = (k + 4) < e;
        int e1 = e - 1;
        a0 = cv[min(k + 8, e1)];
        a1 = cv[min(k + 12, e1)];
        float va0 = __uint_as_float(c0.y);
        float va1 = ok1 ? __uint_as_float(c1.y) : 0.f;
        unsigned col1 = ok1 ? c1.x : c0.x;
        u16x8 x0 = *(const u16x8*)(Xt + (size_t)c0.x * NOUT + l * 8);
        u16x8 x1 = *(const u16x8*)(Xt + (size_t)col1 * NOUT + l * 8);
        #pragma unroll
        for (int i = 0; i < 8; ++i) {
            acc0[i] = fmaf(va0, b2f(x0[i]), acc0[i]);
            acc1[i] = fmaf(va1, b2f(x1[i]), acc1[i]);
        }
    }
    #pragma unroll
    for (int i = 0; i < 8; ++i) {
        float v = acc0[i] + acc1[i];
        v += __shfl_xor(v, 32);
        v += __shfl_xor(v, 16);
        v += bias[l * 8 + i];
        acc0[i] = RELU ? fmaxf(v, 0.f) : v;
    }
    float* accw = acc0;
#endif
    if (qw == 0) {
        u16x8 o;
        #pragma unroll
        for (int i = 0; i < 8; ++i) o[i] = f2b(accw[i]);
        *(u16x8*)(Out + ((size_t)tl * N_NODES + row) * NOUT + l * 8) = o;
    }
}

// ---------------------------------------------------------------------------
// bf16 MFMA GEMM: C[M,Nc] = A[M,K] @ B^T (+bias), out bf16. tile 64x128.
// ---------------------------------------------------------------------------
template<int KC, bool BIAS>
__global__ __launch_bounds__(256) void k_mgemm(
        const u16* __restrict__ A, const u16* __restrict__ B, int ldb,
        const float* __restrict__ bias, u16* __restrict__ C, int ldc, int M) {
    constexpr int K = KC * 32;
    __shared__ bf16x8 frag[8 * KC * 64];
    int tid = threadIdx.x, lane = tid & 63, wave = tid >> 6;
    int m0 = blockIdx.y * 64, n0 = blockIdx.x * 128;

    for (int f = wave; f < 8 * KC; f += 4) {
        int nl = f / KC, kc = f % KC;
        frag[f * 64 + lane] = *(const bf16x8*)(B + (size_t)(n0 + nl * 16 + (lane & 15)) * ldb
                                               + kc * 32 + ((lane >> 4) << 3));
    }
    __syncthreads();

    int arow = m0 + wave * 16 + (lane & 15);
    bool rowok = arow < M;
    const u16* ap = A + (size_t)arow * K + ((lane >> 4) << 3);
    bf16x8 zf = {0, 0, 0, 0, 0, 0, 0, 0};
    bf16x8 af[KC];
    #pragma unroll
    for (int kc = 0; kc < KC; ++kc)
        af[kc] = rowok ? *(const bf16x8*)(ap + kc * 32) : zf;

    f32x4 acc[8] = {};
    #pragma unroll
    for (int kc = 0; kc < KC; ++kc)
        #pragma unroll
        for (int nl = 0; nl < 8; ++nl)
            acc[nl] = __builtin_amdgcn_mfma_f32_16x16x32_bf16(
                af[kc], frag[(nl * KC + kc) * 64 + lane], acc[nl], 0, 0, 0);

    int r0 = m0 + wave * 16 + ((lane >> 4) << 2);
    #pragma unroll
    for (int nl = 0; nl < 8; ++nl) {
        int col = n0 + nl * 16 + (lane & 15);
        float bv = BIAS ? bias[col] : 0.f;
        #pragma unroll
        for (int r = 0; r < 4; ++r) {
            int row = r0 + r;
            if (row < M) C[(size_t)row * ldc + col] = f2b(acc[nl][r] + bv);
        }
    }
}

// ---------------------------------------------------------------------------
// Fused all-16-step GRU v3: wave-specialized, Bg in VGPRs, 32-node blocks.
// 625 blocks (N = 625*32 exactly -> no bounds checks), launch_bounds(512,4)
// pins VGPR<=128 so 2 blocks/CU co-reside. Wave w: quadrant q=w>>1, half
// hb=w&1; its 4 nl-tiles are the gates (r,z,i,n) of hidden slice
// jj=(2q+hb)*16+u. h bf16 double-buffered in padded LDS; h fp32 in regs.
// Fast hw sigmoid/tanh (v_exp+v_rcp). One barrier per step.
// ---------------------------------------------------------------------------
__global__ __launch_bounds__(512, 4) void k_gru_fused3(
        const u16* __restrict__ X2_all, const u16* __restrict__ Bg,
        const float* __restrict__ bgb, float* __restrict__ H) {
    __shared__ u16 hbuf[2][32][132];           // 2 x 8.4 KB, +4 pad
    int tid = threadIdx.x, lane = tid & 63, wave = tid >> 6;
    int q = wave >> 1, hb = wave & 1;
    int u = lane & 15, kgrp = lane >> 4;       // kgrp 0..3
    int m0 = blockIdx.x * 32;
    int jj = (2 * q + hb) * 16 + u;            // this wave's hidden slice col

    // ---- load this wave's 32 B-fragments into registers (once) ----
    bf16x8 bfrag[4][8];
    #pragma unroll
    for (int g = 0; g < 4; ++g)
        #pragma unroll
        for (int kc = 0; kc < 8; ++kc)
            bfrag[g][kc] = *(const bf16x8*)(Bg
                + (size_t)(q * 128 + (4 * hb + g) * 16 + u) * 256
                + kc * 32 + kgrp * 8);

    float bR = bgb[q * 128 + (4 * hb + 0) * 16 + u];
    float bZ = bgb[q * 128 + (4 * hb + 1) * 16 + u];
    float bI = bgb[q * 128 + (4 * hb + 2) * 16 + u];
    float bH = bgb[q * 128 + (4 * hb + 3) * 16 + u];

    for (int i = tid; i < 32 * 132; i += 512) ((u16*)hbuf[0])[i] = 0;

    float hstate[2][4] = {};                   // [tile][r]
    __syncthreads();

    for (int t = 0; t < T_SNAP; ++t) {
        const u16* X2t = X2_all + (size_t)t * N_NODES * NOUT;
        int rb = t & 1, wb = rb ^ 1;
        #pragma unroll
        for (int tile = 0; tile < 2; ++tile) {
            int arow = m0 + tile * 16 + u;
            bf16x8 afx[4], afh[4];
            const u16* a1 = X2t + (size_t)arow * 128 + kgrp * 8;
            #pragma unroll
            for (int kc = 0; kc < 4; ++kc)
                afx[kc] = *(const bf16x8*)(a1 + kc * 32);
            #pragma unroll
            for (int kc = 0; kc < 4; ++kc)
                afh[kc] = *(const bf16x8*)&hbuf[rb][tile * 16 + u][kc * 32 + kgrp * 8];

            f32x4 acc[4] = {};
            #pragma unroll
            for (int kc = 0; kc < 4; ++kc)
                #pragma unroll
                for (int g = 0; g < 4; ++g)
                    acc[g] = __builtin_amdgcn_mfma_f32_16x16x32_bf16(
                        afx[kc], bfrag[g][kc], acc[g], 0, 0, 0);
            #pragma unroll
            for (int kc = 0; kc < 4; ++kc)
                #pragma unroll
                for (int g = 0; g < 4; ++g)
                    acc[g] = __builtin_amdgcn_mfma_f32_16x16x32_bf16(
                        afh[kc], bfrag[g][4 + kc], acc[g], 0, 0, 0);

            #pragma unroll
            for (int r = 0; r < 4; ++r) {
                int lrow = tile * 16 + kgrp * 4 + r;
                float rg = fsig(acc[0][r] + bR);
                float zg = fsig(acc[1][r] + bZ);
                float ng = ftanh(acc[2][r] + bI + rg * (acc[3][r] + bH));
                float hn = (1.f - zg) * ng + zg * hstate[tile][r];
                hstate[tile][r] = hn;
                hbuf[wb][lrow][jj] = f2b(hn);
            }
        }
        __syncthreads();   // wb complete before next step reads it
    }
    #pragma unroll
    for (int tile = 0; tile < 2; ++tile)
        #pragma unroll
        for (int r = 0; r < 4; ++r) {
            int row = m0 + tile * 16 + kgrp * 4 + r;
            H[(size_t)row * HDIM + jj] = hstate[tile][r];
        }
}

// ---------------------------------------------------------------------------
// BatchNorm
// ---------------------------------------------------------------------------
__global__ void k_bnstats(const float* __restrict__ h, float* __restrict__ stats) {
    int j = threadIdx.x;
    int r0 = blockIdx.x * 200;
    float s = 0.f, sq = 0.f;
    for (int r = r0; r < r0 + 200; ++r) {
        float v = h[(size_t)r * HDIM + j];
        s += v; sq += v * v;
    }
    atomicAdd(&stats[j], s);
    atomicAdd(&stats[128 + j], sq);
}

__global__ void k_bnapply(const float* __restrict__ h, const float* __restrict__ stats,
                          const float* __restrict__ gamma, const float* __restrict__ beta,
                          u16* __restrict__ emb) {
    int i = blockIdx.x * 256 + threadIdx.x;
    if (i >= N_NODES * HDIM) return;
    int j = i & 127;
    float mean = stats[j] * (1.f / N_NODES);
    float var  = stats[128 + j] * (1.f / N_NODES) - mean * mean;
    emb[i] = f2b((h[i] - mean) * rsqrtf(var + BN_EPS) * gamma[j] + beta[j]);
}

// ---------------------------------------------------------------------------
// Edge predictor
// ---------------------------------------------------------------------------
__global__ __launch_bounds__(256) void k_edge(const int* __restrict__ edges,
        const u16* __restrict__ P, const u16* __restrict__ Q,
        const float* __restrict__ We2, const float* __restrict__ be2,
        float* __restrict__ out) {
    int e = blockIdx.x * 4 + (threadIdx.x >> 6);
    int lane = threadIdx.x & 63;
    if (e >= EP_EDGES) return;
    int u = edges[e];
    int v = edges[EP_EDGES + e];
    ushort4 pv = *(const ushort4*)(P + (size_t)u * NHID_E + lane * 4);
    ushort4 qv = *(const ushort4*)(Q + (size_t)v * NHID_E + lane * 4);
    const float4* w = (const float4*)(We2 + lane * 8);
    float4 w0 = w[0], w1 = w[1];
    float h0 = fmaxf(b2f(pv.x) + b2f(qv.x), 0.f);
    float h1 = fmaxf(b2f(pv.y) + b2f(qv.y), 0.f);
    float h2 = fmaxf(b2f(pv.z) + b2f(qv.z), 0.f);
    float h3 = fmaxf(b2f(pv.w) + b2f(qv.w), 0.f);
    float l0 = h0 * w0.x + h1 * w0.z + h2 * w1.x + h3 * w1.z;
    float l1 = h0 * w0.y + h1 * w0.w + h2 * w1.y + h3 * w1.w;
    #pragma unroll
    for (int off = 32; off > 0; off >>= 1) {
        l0 += __shfl_down(l0, off);
        l1 += __shfl_down(l1, off);
    }
    if (lane == 0) {
        l0 += be2[0]; l1 += be2[1];
        float m = fmaxf(l0, l1);
        float lse = m + logf(expf(l0 - m) + expf(l1 - m));
        out[(size_t)e * 2 + 0] = l0 - lse;
        out[(size_t)e * 2 + 1] = l1 - lse;
    }
}

// ---------------------------------------------------------------------------
extern "C" void kernel_launch(void* const* d_in, const int* in_sizes, int n_in,
                              void* d_out, int out_size, void* d_ws, size_t ws_size,
                              hipStream_t stream) {
    const int*   adj_rows = (const int*)  d_in[0];
    const int*   adj_cols = (const int*)  d_in[1];
    const float* adj_vals = (const float*)d_in[2];
    const int*   edges    = (const int*)  d_in[3];
    const float* W0   = (const float*)d_in[4];
    const float* b0   = (const float*)d_in[5];
    const float* W1   = (const float*)d_in[6];
    const float* b1   = (const float*)d_in[7];
    const float* W_ih = (const float*)d_in[8];
    const float* W_hh = (const float*)d_in[9];
    const float* b_ih = (const float*)d_in[10];
    const float* b_hh = (const float*)d_in[11];
    const float* gamma = (const float*)d_in[12];
    const float* beta  = (const float*)d_in[13];
    const float* We1  = (const float*)d_in[14];
    const float* be1  = (const float*)d_in[15];
    const float* We2  = (const float*)d_in[16];
    const float* be2  = (const float*)d_in[17];
    float* out = (float*)d_out;

    char* ws = (char*)d_ws;
    size_t off = 0;
    auto alloc = [&](size_t bytes) -> void* {
        void* p = ws + off;
        off += (bytes + 255) & ~(size_t)255;
        return p;
    };
    // ---- persistent ----
    int*   row_ptr = (int*)  alloc((size_t)T_SNAP * (N_NODES + 1) * 4);
    uint2* colval  = (uint2*)alloc((size_t)T_SNAP * E_EDGES * 8);
    u16*   W0_bf   = (u16*)  alloc((size_t)N_NODES * NHID * 2);
    u16*   W1t     = (u16*)  alloc((size_t)NOUT * NHID * 2);
    u16*   We1T    = (u16*)  alloc((size_t)NHID_E * 256 * 2);
    u16*   BgB     = (u16*)  alloc((size_t)512 * 256 * 2);
    float* bgbB    = (float*)alloc(512 * 4);
    float* h       = (float*)alloc((size_t)N_NODES * HDIM * 4);
    float* stats   = (float*)alloc(256 * 4);
    int*   bcnt    = (int*)  alloc((size_t)T_SNAP * NBUCK * 4);
    int*   bbase   = (int*)  alloc((size_t)T_SNAP * NBUCK * 4);
    int*   ovf_cnt = (int*)  alloc(256);
    size_t mark = off;

    // ---- union region: CSR phase ----
    off = mark;
    uint2* staging = (uint2*)alloc((size_t)T_SNAP * NBUCK * BCAP * 8);
    uint4* ovf     = (uint4*)alloc((size_t)T_SNAP * E_EDGES * 16);
    size_t csr_end = off;

    // ---- union region: compute phase (BT adaptive 8 -> 4) ----
    int BT = 8;
    u16 *X0_b, *Y_b, *X2_all;
    size_t comp_end;
    for (;;) {
        off = mark;
        X0_b   = (u16*)alloc((size_t)BT * N_NODES * NHID * 2);
        Y_b    = (u16*)alloc((size_t)BT * N_NODES * NOUT * 2);
        X2_all = (u16*)alloc((size_t)T_SNAP * N_NODES * NOUT * 2);
        comp_end = off;
        if (comp_end <= ws_size || BT == 4) break;
        BT >>= 1;
    }

    // ---- union region: post phase (X0_b/Y_b dead; X2_all beyond them survives
    //      through GRU; emb/P/Q fit inside the dead X0_b area) ----
    off = mark;
    u16* emb = (u16*)alloc((size_t)N_NODES * HDIM * 2);
    u16* P   = (u16*)alloc((size_t)N_NODES * NHID_E * 2);
    u16* Q   = (u16*)alloc((size_t)N_NODES * NHID_E * 2);
    size_t post_end = off;

    size_t need = csr_end;
    if (comp_end > need) need = comp_end;
    if (post_end > need) need = post_end;
    if (need > ws_size) return;   // visible failure instead of corruption

    hipMemsetAsync(bcnt,    0, (size_t)T_SNAP * NBUCK * 4, stream);
    hipMemsetAsync(ovf_cnt, 0, 256, stream);
    hipMemsetAsync(stats,   0, 256 * 4, stream);

    // ---- CSR build v2 ----
    dim3 p1g((E_EDGES + P1CHUNK - 1) / P1CHUNK, T_SNAP);
    k_p1   <<<p1g, 256, 0, stream>>>(adj_rows, adj_cols, adj_vals, bcnt, staging, ovf, ovf_cnt);
    k_bscan<<<1, 256, 0, stream>>>(bcnt, bbase, row_ptr);
    k_p2   <<<dim3(NBUCK, T_SNAP), 256, 0, stream>>>(bcnt, bbase, staging, ovf, ovf_cnt,
                                                     colval, row_ptr);

    // ---- weight conversions ----
    k_cvt      <<<(N_NODES * NHID / 4 + 255) / 256, 256, 0, stream>>>(W0, W0_bf, N_NODES * NHID / 4);
    k_tcvt     <<<(NHID * NOUT + 255) / 256,  256, 0, stream>>>(W1, W1t, NHID, NOUT);
    k_tcvt     <<<(256 * NHID_E + 255) / 256, 256, 0, stream>>>(We1, We1T, 256, NHID_E);
    k_build_bg <<<(512 * 256 + 255) / 256, 256, 0, stream>>>(W_ih, W_hh, BgB);
    k_build_bgb<<<2, 256, 0, stream>>>(b_ih, b_hh, bgbB);

    // ---- batched GCN: layer0 spmm -> X0@W1 -> layer1 spmm -> X2_all ----
    for (int g = 0; g < T_SNAP; g += BT) {
        k_spmm0<true><<<dim3(N_NODES / 4, BT), 256, 0, stream>>>(
            row_ptr, colval, g, W0_bf, b0, X0_b);
        int M = BT * N_NODES;
        k_mgemm<8, false><<<dim3(1, (M + 63) / 64), 256, 0, stream>>>(
            X0_b, W1t, NHID, nullptr, Y_b, NOUT, M);
        k_spmm1<false><<<dim3(N_NODES / 4, BT), 256, 0, stream>>>(
            row_ptr, colval, g, Y_b, (size_t)N_NODES * NOUT, b1,
            X2_all + (size_t)g * N_NODES * NOUT);
    }

    // ---- GRU: all 16 steps fused, Bg in VGPRs, 625 blocks ----
    k_gru_fused3<<<N_NODES / 32, 512, 0, stream>>>(X2_all, BgB, bgbB, h);

    // ---- BatchNorm ----
    k_bnstats<<<100, 128, 0, stream>>>(h, stats);
    k_bnapply<<<(N_NODES * HDIM + 255) / 256, 256, 0, stream>>>(h, stats, gamma, beta, emb);

    // ---- Edge MLP precompute + predictor ----
    k_mgemm<4, true><<<dim3(2, (N_NODES + 63) / 64), 256, 0, stream>>>(
        emb, We1T, 256, be1, P, NHID_E, N_NODES);
    k_mgemm<4, false><<<dim3(2, (N_NODES + 63) / 64), 256, 0, stream>>>(
        emb, We1T + 128, 256, nullptr, Q, NHID_E, N_NODES);
    k_edge<<<(EP_EDGES + 3) / 4, 256, 0, stream>>>(edges, P, Q, We2, be2, out);
}

// Round 14
// 890.373 us; speedup vs baseline: 1.2687x; 1.2687x over previous
//
#include <hip/hip_runtime.h>
#include <math.h>

#define N_NODES 20000
#define NHID    256
#define NOUT    128
#define HDIM    128
#define NHID_E  256
#define T_SNAP  16
#define E_EDGES 320000
#define EP_EDGES 100000
#define BN_EPS  1e-5f

#define BROWS 128                    // rows per bucket
#define NBUCK 157                    // ceil(N_NODES / BROWS)
#define BCAP  4096                   // staging capacity per bucket
#define P1CHUNK 2048                 // edges per k_p1 block (25KB LDS -> 6 blk/CU)

typedef unsigned short u16;
typedef __attribute__((ext_vector_type(8))) short bf16x8;
typedef __attribute__((ext_vector_type(8))) unsigned short u16x8;
typedef __attribute__((ext_vector_type(4))) float f32x4;

__device__ __forceinline__ u16 f2b(float f) {
    unsigned u = __float_as_uint(f);
    u += 0x7FFFu + ((u >> 16) & 1u);
    return (u16)(u >> 16);
}
__device__ __forceinline__ float b2f(u16 s) { return __uint_as_float(((unsigned)s) << 16); }

// ---- fast transcendentals (v_exp_f32 / v_rcp_f32), guarded ----
__device__ __forceinline__ float fexp2(float x) {
#if __has_builtin(__builtin_amdgcn_exp2f)
    return __builtin_amdgcn_exp2f(x);
#else
    return exp2f(x);
#endif
}
__device__ __forceinline__ float frcp(float x) {
#if __has_builtin(__builtin_amdgcn_rcpf)
    return __builtin_amdgcn_rcpf(x);
#else
    return 1.f / x;
#endif
}
__device__ __forceinline__ float fsig(float x) {
    return frcp(1.f + fexp2(x * -1.4426950408889634f));
}
__device__ __forceinline__ float ftanh(float x) {
    float t = fexp2(x * 2.8853900817779268f);
    return 1.f - 2.f * frcp(t + 1.f);
}

// ---- bf16 dot2 path (guarded; falls back to shl+fma if builtin absent) ----
#if __has_builtin(__builtin_amdgcn_fdot2_f32_bf16)
#define HAVE_DOT2 1
typedef __attribute__((ext_vector_type(2))) __bf16 bf2v;
__device__ __forceinline__ float dot2b(unsigned x, unsigned v, float acc) {
    return __builtin_amdgcn_fdot2_f32_bf16(
        __builtin_bit_cast(bf2v, x), __builtin_bit_cast(bf2v, v), acc, false);
}
__device__ __forceinline__ unsigned pack_lo(unsigned a, unsigned b) {
#if __has_builtin(__builtin_amdgcn_perm)
    return __builtin_amdgcn_perm(a, b, 0x01000504u);   // (a.e0 | b.e0<<16)
#else
    return (a & 0xFFFFu) | (b << 16);
#endif
}
__device__ __forceinline__ unsigned pack_hi(unsigned a, unsigned b) {
#if __has_builtin(__builtin_amdgcn_perm)
    return __builtin_amdgcn_perm(a, b, 0x03020706u);   // (a.e1 | b.e1<<16)
#else
    return (a >> 16) | (b & 0xFFFF0000u);
#endif
}
#else
#define HAVE_DOT2 0
#endif

// ---------------------------------------------------------------------------
// CSR build v2, phase 1: block-local counting sort by bucket, append runs.
// ---------------------------------------------------------------------------
__global__ __launch_bounds__(256) void k_p1(const int* __restrict__ rows,
        const int* __restrict__ cols, const float* __restrict__ vals,
        int* __restrict__ bcnt, uint2* __restrict__ staging,
        uint4* __restrict__ ovf, int* __restrict__ ovf_cnt) {
    int t = blockIdx.y;
    int base = blockIdx.x * P1CHUNK;
    int tid = threadIdx.x;
    __shared__ int hist[256], sc[256], excl[256], cursor[256], gbase[256];
    __shared__ uint2 ebuf[P1CHUNK];
    __shared__ u16 ebuck[P1CHUNK];
    hist[tid] = 0;
    __syncthreads();
    const int*   rt = rows + (size_t)t * E_EDGES;
    const int*   ct = cols + (size_t)t * E_EDGES;
    const float* vt = vals + (size_t)t * E_EDGES;
    #pragma unroll
    for (int k = 0; k < P1CHUNK / 256; ++k) {
        int i = base + k * 256 + tid;
        if (i < E_EDGES) atomicAdd(&hist[rt[i] >> 7], 1);
    }
    __syncthreads();
    sc[tid] = hist[tid];
    __syncthreads();
    for (int off = 1; off < 256; off <<= 1) {
        int add = (tid >= off) ? sc[tid - off] : 0;
        __syncthreads();
        sc[tid] += add;
        __syncthreads();
    }
    excl[tid]   = sc[tid] - hist[tid];
    cursor[tid] = sc[tid] - hist[tid];
    __syncthreads();
    #pragma unroll
    for (int k = 0; k < P1CHUNK / 256; ++k) {
        int i = base + k * 256 + tid;
        if (i < E_EDGES) {
            int r = rt[i];
            int b = r >> 7;
            int s = atomicAdd(&cursor[b], 1);
            uint2 e;
            e.x = (unsigned)ct[i] | ((unsigned)(r & 127) << 15);
            e.y = __float_as_uint(vt[i]);
            ebuf[s]  = e;
            ebuck[s] = (u16)b;
        }
    }
    __syncthreads();
    if (hist[tid] > 0) gbase[tid] = atomicAdd(&bcnt[t * NBUCK + tid], hist[tid]);
    __syncthreads();
    int nvalid = min(P1CHUNK, E_EDGES - base);
    for (int s = tid; s < nvalid; s += 256) {
        int b = ebuck[s];
        int g = gbase[b] + (s - excl[b]);
        if (g < BCAP) {
            staging[((size_t)t * NBUCK + b) * BCAP + g] = ebuf[s];
        } else {
            int o = atomicAdd(ovf_cnt, 1);
            uint4 e4; e4.x = (unsigned)(t * NBUCK + b); e4.y = ebuf[s].x; e4.z = ebuf[s].y; e4.w = 0;
            ovf[o] = e4;
        }
    }
}

// phase 2a: exclusive scan of all bucket counts (2512 values), one block
__global__ void k_bscan(const int* __restrict__ bcnt, int* __restrict__ bbase,
                        int* __restrict__ row_ptr) {
    __shared__ int sh[256];
    __shared__ int carry;
    int tid = threadIdx.x;
    if (tid == 0) carry = 0;
    __syncthreads();
    for (int b0 = 0; b0 < T_SNAP * NBUCK; b0 += 256) {
        int i = b0 + tid;
        int v = (i < T_SNAP * NBUCK) ? bcnt[i] : 0;
        sh[tid] = v;
        __syncthreads();
        for (int off = 1; off < 256; off <<= 1) {
            int add = (tid >= off) ? sh[tid - off] : 0;
            __syncthreads();
            sh[tid] += add;
            __syncthreads();
        }
        if (i < T_SNAP * NBUCK) bbase[i] = carry + sh[tid] - v;
        __syncthreads();
        if (tid == 255) carry += sh[255];
        __syncthreads();
    }
    if (tid < T_SNAP) row_ptr[tid * (N_NODES + 1) + N_NODES] = E_EDGES;
}

// phase 2b: per-bucket row sort -> row_ptr + final colval
__global__ __launch_bounds__(256) void k_p2(const int* __restrict__ bcnt,
        const int* __restrict__ bbase, const uint2* __restrict__ staging,
        const uint4* __restrict__ ovf, const int* __restrict__ ovf_cnt,
        uint2* __restrict__ colval, int* __restrict__ row_ptr) {
    int b = blockIdx.x, t = blockIdx.y, tid = threadIdx.x;
    int idx = t * NBUCK + b;
    int cnt = bcnt[idx];
    int gb  = bbase[idx];
    __shared__ int hist[BROWS], cursor[BROWS], sc[BROWS];
    if (tid < BROWS) hist[tid] = 0;
    __syncthreads();
    int staged = min(cnt, BCAP);
    const uint2* st = staging + (size_t)idx * BCAP;
    for (int s = tid; s < staged; s += 256)
        atomicAdd(&hist[st[s].x >> 15], 1);
    int nov = (cnt > staged) ? *ovf_cnt : 0;
    for (int o = tid; o < nov; o += 256) {
        uint4 e = ovf[o];
        if ((int)e.x == idx) atomicAdd(&hist[(e.y >> 15) & 127], 1);
    }
    __syncthreads();
    if (tid < BROWS) sc[tid] = hist[tid];
    __syncthreads();
    for (int off = 1; off < BROWS; off <<= 1) {
        int add = (tid < BROWS && tid >= off) ? sc[tid - off] : 0;
        __syncthreads();
        if (tid < BROWS) sc[tid] += add;
        __syncthreads();
    }
    if (tid < BROWS) {
        int ex = sc[tid] - hist[tid];
        cursor[tid] = ex;
        int row = b * BROWS + tid;
        if (row < N_NODES)
            row_ptr[t * (N_NODES + 1) + row] = gb - t * E_EDGES + ex;
    }
    __syncthreads();
    for (int s = tid; s < staged; s += 256) {
        uint2 e = st[s];
        int rl = e.x >> 15;
        int pos = atomicAdd(&cursor[rl], 1);
        uint2 o2; o2.x = e.x & 0x7FFF; o2.y = e.y;
        colval[(size_t)gb + pos] = o2;
    }
    for (int o = tid; o < nov; o += 256) {
        uint4 e = ovf[o];
        if ((int)e.x == idx) {
            int rl = (e.y >> 15) & 127;
            int pos = atomicAdd(&cursor[rl], 1);
            uint2 o2; o2.x = e.y & 0x7FFF; o2.y = e.z;
            colval[(size_t)gb + pos] = o2;
        }
    }
}

// ---------------------------------------------------------------------------
// Conversions / weight builders
// ---------------------------------------------------------------------------
__global__ void k_cvt(const float* __restrict__ in, u16* __restrict__ out, int n4) {
    int i = blockIdx.x * 256 + threadIdx.x;
    if (i < n4) {
        float4 v = ((const float4*)in)[i];
        ushort4 o;
        o.x = f2b(v.x); o.y = f2b(v.y); o.z = f2b(v.z); o.w = f2b(v.w);
        ((ushort4*)out)[i] = o;
    }
}

__global__ void k_tcvt(const float* __restrict__ in, u16* __restrict__ out, int Kr, int Nc) {
    int i = blockIdx.x * 256 + threadIdx.x;
    if (i < Kr * Nc) {
        int k = i / Nc, n = i - k * Nc;
        out[(size_t)n * Kr + k] = f2b(in[i]);
    }
}

// 512-col interleave over concat(x,h)
__global__ void k_build_bg(const float* __restrict__ Wih, const float* __restrict__ Whh,
                           u16* __restrict__ Bg) {
    int i = blockIdx.x * 256 + threadIdx.x;
    if (i >= 512 * 256) return;
    int rr = i >> 8, k = i & 255;
    int c = rr >> 4, u = rr & 15, g = c & 3, jj = ((c >> 2) << 4) + u;
    float v;
    if (g == 0)      v = (k < 128) ? Wih[(size_t)jj * 128 + k]         : Whh[(size_t)jj * 128 + k - 128];
    else if (g == 1) v = (k < 128) ? Wih[(size_t)(128 + jj) * 128 + k] : Whh[(size_t)(128 + jj) * 128 + k - 128];
    else if (g == 2) v = (k < 128) ? Wih[(size_t)(256 + jj) * 128 + k] : 0.f;
    else             v = (k < 128) ? 0.f : Whh[(size_t)(256 + jj) * 128 + k - 128];
    Bg[i] = f2b(v);
}

__global__ void k_build_bgb(const float* __restrict__ bih, const float* __restrict__ bhh,
                            float* __restrict__ bgb) {
    int rr = blockIdx.x * 256 + threadIdx.x;
    if (rr >= 512) return;
    int c = rr >> 4, u = rr & 15, g = c & 3, jj = ((c >> 2) << 4) + u;
    float v;
    if (g == 0)      v = bih[jj] + bhh[jj];
    else if (g == 1) v = bih[128 + jj] + bhh[128 + jj];
    else if (g == 2) v = bih[256 + jj];
    else             v = bhh[256 + jj];
    bgb[rr] = v;
}

// ---------------------------------------------------------------------------
// SpMM layer0 (D=256): one row per wave, half-wave per edge stream, 2 streams
// (r7 version — at the random-gather memory-path roofline).
// ---------------------------------------------------------------------------
template<bool RELU>
__global__ __launch_bounds__(256) void k_spmm0(
        const int* __restrict__ rp_all, const uint2* __restrict__ cv_all,
        int t0, const u16* __restrict__ X,
        const float* __restrict__ bias, u16* __restrict__ Out) {
    int lane = threadIdx.x & 63;
    int row = blockIdx.x * 4 + (threadIdx.x >> 6);
    int tl = blockIdx.y, t = t0 + tl;
    const int*   rp = rp_all + (size_t)t * (N_NODES + 1);
    const uint2* cv = cv_all + (size_t)t * E_EDGES;
    int hw = lane >> 5, l = lane & 31;
    int s = rp[row], e = rp[row + 1];
    int k = s + hw;
    uint2 a0 = make_uint2(0u, 0u), a1 = make_uint2(0u, 0u);
    if (k < e)     a0 = cv[k];
    if (k + 2 < e) a1 = cv[k + 2];
#if HAVE_DOT2
    float acc[8] = {};
    for (; k < e; k += 4) {
        uint2 c0 = a0, c1 = a1;
        bool ok1 = (k + 2) < e;
        int e1 = e - 1;
        a0 = cv[min(k + 4, e1)];
        a1 = cv[min(k + 6, e1)];
        unsigned col1 = ok1 ? c1.x : c0.x;
        float va1f = ok1 ? __uint_as_float(c1.y) : 0.f;
        unsigned vv = (unsigned)f2b(__uint_as_float(c0.y)) | ((unsigned)f2b(va1f) << 16);
        uint4 x0 = *(const uint4*)(X + (size_t)c0.x * NHID + l * 8);
        uint4 x1 = *(const uint4*)(X + (size_t)col1 * NHID + l * 8);
        acc[0] = dot2b(pack_lo(x0.x, x1.x), vv, acc[0]);
        acc[1] = dot2b(pack_hi(x0.x, x1.x), vv, acc[1]);
        acc[2] = dot2b(pack_lo(x0.y, x1.y), vv, acc[2]);
        acc[3] = dot2b(pack_hi(x0.y, x1.y), vv, acc[3]);
        acc[4] = dot2b(pack_lo(x0.z, x1.z), vv, acc[4]);
        acc[5] = dot2b(pack_hi(x0.z, x1.z), vv, acc[5]);
        acc[6] = dot2b(pack_lo(x0.w, x1.w), vv, acc[6]);
        acc[7] = dot2b(pack_hi(x0.w, x1.w), vv, acc[7]);
    }
    #pragma unroll
    for (int i = 0; i < 8; ++i) {
        float v = acc[i];
        v += __shfl_xor(v, 32);
        v += bias[l * 8 + i];
        acc[i] = RELU ? fmaxf(v, 0.f) : v;
    }
    float* accw = acc;
#else
    float acc0[8] = {}, acc1[8] = {};
    for (; k < e; k += 4) {
        uint2 c0 = a0, c1 = a1;
        bool ok1 = (k + 2) < e;
        int e1 = e - 1;
        a0 = cv[min(k + 4, e1)];
        a1 = cv[min(k + 6, e1)];
        float va0 = __uint_as_float(c0.y);
        float va1 = ok1 ? __uint_as_float(c1.y) : 0.f;
        unsigned col1 = ok1 ? c1.x : c0.x;
        u16x8 x0 = *(const u16x8*)(X + (size_t)c0.x * NHID + l * 8);
        u16x8 x1 = *(const u16x8*)(X + (size_t)col1 * NHID + l * 8);
        #pragma unroll
        for (int i = 0; i < 8; ++i) {
            acc0[i] = fmaf(va0, b2f(x0[i]), acc0[i]);
            acc1[i] = fmaf(va1, b2f(x1[i]), acc1[i]);
        }
    }
    #pragma unroll
    for (int i = 0; i < 8; ++i) {
        float v = acc0[i] + acc1[i];
        v += __shfl_xor(v, 32);
        v += bias[l * 8 + i];
        acc0[i] = RELU ? fmaxf(v, 0.f) : v;
    }
    float* accw = acc0;
#endif
    if (hw == 0) {
        u16x8 o;
        #pragma unroll
        for (int i = 0; i < 8; ++i) o[i] = f2b(accw[i]);
        *(u16x8*)(Out + ((size_t)tl * N_NODES + row) * NHID + l * 8) = o;
    }
}

// ---------------------------------------------------------------------------
// SpMM layer1 (D=128): quarter-wave per edge stream, 2 streams (r7 version).
// ---------------------------------------------------------------------------
template<bool RELU>
__global__ __launch_bounds__(256) void k_spmm1(
        const int* __restrict__ rp_all, const uint2* __restrict__ cv_all,
        int t0, const u16* __restrict__ X, size_t xtstride,
        const float* __restrict__ bias, u16* __restrict__ Out) {
    int lane = threadIdx.x & 63;
    int row = blockIdx.x * 4 + (threadIdx.x >> 6);
    int tl = blockIdx.y, t = t0 + tl;
    const int*   rp = rp_all + (size_t)t * (N_NODES + 1);
    const uint2* cv = cv_all + (size_t)t * E_EDGES;
    const u16*   Xt = X + xtstride * tl;
    int qw = lane >> 4, l = lane & 15;
    int s = rp[row], e = rp[row + 1];
    int k = s + qw;
    uint2 a0 = make_uint2(0u, 0u), a1 = make_uint2(0u, 0u);
    if (k < e)     a0 = cv[k];
    if (k + 4 < e) a1 = cv[k + 4];
#if HAVE_DOT2
    float acc[8] = {};
    for (; k < e; k += 8) {
        uint2 c0 = a0, c1 = a1;
        bool ok1 = (k + 4) < e;
        int e1 = e - 1;
        a0 = cv[min(k + 8, e1)];
        a1 = cv[min(k + 12, e1)];
        unsigned col1 = ok1 ? c1.x : c0.x;
        float va1f = ok1 ? __uint_as_float(c1.y) : 0.f;
        unsigned vv = (unsigned)f2b(__uint_as_float(c0.y)) | ((unsigned)f2b(va1f) << 16);
        uint4 x0 = *(const uint4*)(Xt + (size_t)c0.x * NOUT + l * 8);
        uint4 x1 = *(const uint4*)(Xt + (size_t)col1 * NOUT + l * 8);
        acc[0] = dot2b(pack_lo(x0.x, x1.x), vv, acc[0]);
        acc[1] = dot2b(pack_hi(x0.x, x1.x), vv, acc[1]);
        acc[2] = dot2b(pack_lo(x0.y, x1.y), vv, acc[2]);
        acc[3] = dot2b(pack_hi(x0.y, x1.y), vv, acc[3]);
        acc[4] = dot2b(pack_lo(x0.z, x1.z), vv, acc[4]);
        acc[5] = dot2b(pack_hi(x0.z, x1.z), vv, acc[5]);
        acc[6] = dot2b(pack_lo(x0.w, x1.w), vv, acc[6]);
        acc[7] = dot2b(pack_hi(x0.w, x1.w), vv, acc[7]);
    }
    #pragma unroll
    for (int i = 0; i < 8; ++i) {
        float v = acc[i];
        v += __shfl_xor(v, 32);
        v += __shfl_xor(v, 16);
        v += bias[l * 8 + i];
        acc[i] = RELU ? fmaxf(v, 0.f) : v;
    }
    float* accw = acc;
#else
    float acc0[8] = {}, acc1[8] = {};
    for (; k < e; k += 8) {
        uint2 c0 = a0, c1 = a1;
        bool ok1 = (k + 4) < e;
        int e1 = e - 1;
        a0 = cv[min(k + 8, e1)];
        a1 = cv[min(k + 12, e1)];
        float va0 = __uint_as_float(c0.y);
        float va1 = ok1 ? __uint_as_float(c1.y) : 0.f;
        unsigned col1 = ok1 ? c1.x : c0.x;
        u16x8 x0 = *(const u16x8*)(Xt + (size_t)c0.x * NOUT + l * 8);
        u16x8 x1 = *(const u16x8*)(Xt + (size_t)col1 * NOUT + l * 8);
        #pragma unroll
        for (int i = 0; i < 8; ++i) {
            acc0[i] = fmaf(va0, b2f(x0[i]), acc0[i]);
            acc1[i] = fmaf(va1, b2f(x1[i]), acc1[i]);
        }
    }
    #pragma unroll
    for (int i = 0; i < 8; ++i) {
        float v = acc0[i] + acc1[i];
        v += __shfl_xor(v, 32);
        v += __shfl_xor(v, 16);
        v += bias[l * 8 + i];
        acc0[i] = RELU ? fmaxf(v, 0.f) : v;
    }
    float* accw = acc0;
#endif
    if (qw == 0) {
        u16x8 o;
        #pragma unroll
        for (int i = 0; i < 8; ++i) o[i] = f2b(accw[i]);
        *(u16x8*)(Out + ((size_t)tl * N_NODES + row) * NOUT + l * 8) = o;
    }
}

// ---------------------------------------------------------------------------
// bf16 MFMA GEMM: C[M,Nc] = A[M,K] @ B^T (+bias), out bf16. tile 64x128.
// ---------------------------------------------------------------------------
template<int KC, bool BIAS>
__global__ __launch_bounds__(256) void k_mgemm(
        const u16* __restrict__ A, const u16* __restrict__ B, int ldb,
        const float* __restrict__ bias, u16* __restrict__ C, int ldc, int M) {
    constexpr int K = KC * 32;
    __shared__ bf16x8 frag[8 * KC * 64];
    int tid = threadIdx.x, lane = tid & 63, wave = tid >> 6;
    int m0 = blockIdx.y * 64, n0 = blockIdx.x * 128;

    for (int f = wave; f < 8 * KC; f += 4) {
        int nl = f / KC, kc = f % KC;
        frag[f * 64 + lane] = *(const bf16x8*)(B + (size_t)(n0 + nl * 16 + (lane & 15)) * ldb
                                               + kc * 32 + ((lane >> 4) << 3));
    }
    __syncthreads();

    int arow = m0 + wave * 16 + (lane & 15);
    bool rowok = arow < M;
    const u16* ap = A + (size_t)arow * K + ((lane >> 4) << 3);
    bf16x8 zf = {0, 0, 0, 0, 0, 0, 0, 0};
    bf16x8 af[KC];
    #pragma unroll
    for (int kc = 0; kc < KC; ++kc)
        af[kc] = rowok ? *(const bf16x8*)(ap + kc * 32) : zf;

    f32x4 acc[8] = {};
    #pragma unroll
    for (int kc = 0; kc < KC; ++kc)
        #pragma unroll
        for (int nl = 0; nl < 8; ++nl)
            acc[nl] = __builtin_amdgcn_mfma_f32_16x16x32_bf16(
                af[kc], frag[(nl * KC + kc) * 64 + lane], acc[nl], 0, 0, 0);

    int r0 = m0 + wave * 16 + ((lane >> 4) << 2);
    #pragma unroll
    for (int nl = 0; nl < 8; ++nl) {
        int col = n0 + nl * 16 + (lane & 15);
        float bv = BIAS ? bias[col] : 0.f;
        #pragma unroll
        for (int r = 0; r < 4; ++r) {
            int row = r0 + r;
            if (row < M) C[(size_t)row * ldc + col] = f2b(acc[nl][r] + bv);
        }
    }
}

// ---------------------------------------------------------------------------
// Fused all-16-step GRU (r12 geometry, fast transcendentals): wave-specialized,
// Bg resident in VGPRs. Block = 64 nodes, 512 thr / 8 waves,
// launch_bounds(512,2) -- measured r12: VGPR 116, no spill, FETCH 42 MB.
// Wave w: quadrant q=w>>1, half hb=w&1; its 4 nl-tiles are the 4 gates
// (r,z,i,n) of hidden slice jj=(2q+hb)*16+u. h bf16 double-buffered in padded
// LDS; h fp32 state in regs. One barrier per step.
// ---------------------------------------------------------------------------
__global__ __launch_bounds__(512, 2) void k_gru_fused2(
        const u16* __restrict__ X2_all, const u16* __restrict__ Bg,
        const float* __restrict__ bgb, float* __restrict__ H) {
    __shared__ u16 hbuf[2][64][132];           // 2 x 16.9 KB, +4 pad
    int tid = threadIdx.x, lane = tid & 63, wave = tid >> 6;
    int q = wave >> 1, hb = wave & 1;
    int u = lane & 15, kgrp = lane >> 4;       // kgrp 0..3
    int m0 = blockIdx.x * 64;
    int jj = (2 * q + hb) * 16 + u;            // this wave's hidden slice col

    // ---- load this wave's 32 B-fragments into registers (once) ----
    bf16x8 bfrag[4][8];
    #pragma unroll
    for (int g = 0; g < 4; ++g)
        #pragma unroll
        for (int kc = 0; kc < 8; ++kc)
            bfrag[g][kc] = *(const bf16x8*)(Bg
                + (size_t)(q * 128 + (4 * hb + g) * 16 + u) * 256
                + kc * 32 + kgrp * 8);

    float bR = bgb[q * 128 + (4 * hb + 0) * 16 + u];
    float bZ = bgb[q * 128 + (4 * hb + 1) * 16 + u];
    float bI = bgb[q * 128 + (4 * hb + 2) * 16 + u];
    float bH = bgb[q * 128 + (4 * hb + 3) * 16 + u];

    for (int i = tid; i < 64 * 132; i += 512) ((u16*)hbuf[0])[i] = 0;

    float hstate[4][4] = {};                   // [tile][r]
    bf16x8 zf = {0, 0, 0, 0, 0, 0, 0, 0};
    __syncthreads();

    for (int t = 0; t < T_SNAP; ++t) {
        const u16* X2t = X2_all + (size_t)t * N_NODES * NOUT;
        int rb = t & 1, wb = rb ^ 1;
        #pragma unroll
        for (int tile = 0; tile < 4; ++tile) {
            int arow = m0 + tile * 16 + u;
            bool rowok = arow < N_NODES;
            bf16x8 afx[4], afh[4];
            const u16* a1 = X2t + (size_t)arow * 128 + kgrp * 8;
            #pragma unroll
            for (int kc = 0; kc < 4; ++kc)
                afx[kc] = rowok ? *(const bf16x8*)(a1 + kc * 32) : zf;
            #pragma unroll
            for (int kc = 0; kc < 4; ++kc)
                afh[kc] = *(const bf16x8*)&hbuf[rb][tile * 16 + u][kc * 32 + kgrp * 8];

            f32x4 acc[4] = {};
            #pragma unroll
            for (int kc = 0; kc < 4; ++kc)
                #pragma unroll
                for (int g = 0; g < 4; ++g)
                    acc[g] = __builtin_amdgcn_mfma_f32_16x16x32_bf16(
                        afx[kc], bfrag[g][kc], acc[g], 0, 0, 0);
            #pragma unroll
            for (int kc = 0; kc < 4; ++kc)
                #pragma unroll
                for (int g = 0; g < 4; ++g)
                    acc[g] = __builtin_amdgcn_mfma_f32_16x16x32_bf16(
                        afh[kc], bfrag[g][4 + kc], acc[g], 0, 0, 0);

            #pragma unroll
            for (int r = 0; r < 4; ++r) {
                int lrow = tile * 16 + kgrp * 4 + r;
                if (m0 + lrow >= N_NODES) continue;
                float rg = fsig(acc[0][r] + bR);
                float zg = fsig(acc[1][r] + bZ);
                float ng = ftanh(acc[2][r] + bI + rg * (acc[3][r] + bH));
                float hn = (1.f - zg) * ng + zg * hstate[tile][r];
                hstate[tile][r] = hn;
                hbuf[wb][lrow][jj] = f2b(hn);
            }
        }
        __syncthreads();   // wb complete before next step reads it
    }
    #pragma unroll
    for (int tile = 0; tile < 4; ++tile)
        #pragma unroll
        for (int r = 0; r < 4; ++r) {
            int row = m0 + tile * 16 + kgrp * 4 + r;
            if (row < N_NODES) H[(size_t)row * HDIM + jj] = hstate[tile][r];
        }
}

// ---------------------------------------------------------------------------
// BatchNorm
// ---------------------------------------------------------------------------
__global__ void k_bnstats(const float* __restrict__ h, float* __restrict__ stats) {
    int j = threadIdx.x;
    int r0 = blockIdx.x * 200;
    float s = 0.f, sq = 0.f;
    for (int r = r0; r < r0 + 200; ++r) {
        float v = h[(size_t)r * HDIM + j];
        s += v; sq += v * v;
    }
    atomicAdd(&stats[j], s);
    atomicAdd(&stats[128 + j], sq);
}

__global__ void k_bnapply(const float* __restrict__ h, const float* __restrict__ stats,
                          const float* __restrict__ gamma, const float* __restrict__ beta,
                          u16* __restrict__ emb) {
    int i = blockIdx.x * 256 + threadIdx.x;
    if (i >= N_NODES * HDIM) return;
    int j = i & 127;
    float mean = stats[j] * (1.f / N_NODES);
    float var  = stats[128 + j] * (1.f / N_NODES) - mean * mean;
    emb[i] = f2b((h[i] - mean) * rsqrtf(var + BN_EPS) * gamma[j] + beta[j]);
}

// ---------------------------------------------------------------------------
// Edge predictor
// ---------------------------------------------------------------------------
__global__ __launch_bounds__(256) void k_edge(const int* __restrict__ edges,
        const u16* __restrict__ P, const u16* __restrict__ Q,
        const float* __restrict__ We2, const float* __restrict__ be2,
        float* __restrict__ out) {
    int e = blockIdx.x * 4 + (threadIdx.x >> 6);
    int lane = threadIdx.x & 63;
    if (e >= EP_EDGES) return;
    int u = edges[e];
    int v = edges[EP_EDGES + e];
    ushort4 pv = *(const ushort4*)(P + (size_t)u * NHID_E + lane * 4);
    ushort4 qv = *(const ushort4*)(Q + (size_t)v * NHID_E + lane * 4);
    const float4* w = (const float4*)(We2 + lane * 8);
    float4 w0 = w[0], w1 = w[1];
    float h0 = fmaxf(b2f(pv.x) + b2f(qv.x), 0.f);
    float h1 = fmaxf(b2f(pv.y) + b2f(qv.y), 0.f);
    float h2 = fmaxf(b2f(pv.z) + b2f(qv.z), 0.f);
    float h3 = fmaxf(b2f(pv.w) + b2f(qv.w), 0.f);
    float l0 = h0 * w0.x + h1 * w0.z + h2 * w1.x + h3 * w1.z;
    float l1 = h0 * w0.y + h1 * w0.w + h2 * w1.y + h3 * w1.w;
    #pragma unroll
    for (int off = 32; off > 0; off >>= 1) {
        l0 += __shfl_down(l0, off);
        l1 += __shfl_down(l1, off);
    }
    if (lane == 0) {
        l0 += be2[0]; l1 += be2[1];
        float m = fmaxf(l0, l1);
        float lse = m + logf(expf(l0 - m) + expf(l1 - m));
        out[(size_t)e * 2 + 0] = l0 - lse;
        out[(size_t)e * 2 + 1] = l1 - lse;
    }
}

// ---------------------------------------------------------------------------
extern "C" void kernel_launch(void* const* d_in, const int* in_sizes, int n_in,
                              void* d_out, int out_size, void* d_ws, size_t ws_size,
                              hipStream_t stream) {
    const int*   adj_rows = (const int*)  d_in[0];
    const int*   adj_cols = (const int*)  d_in[1];
    const float* adj_vals = (const float*)d_in[2];
    const int*   edges    = (const int*)  d_in[3];
    const float* W0   = (const float*)d_in[4];
    const float* b0   = (const float*)d_in[5];
    const float* W1   = (const float*)d_in[6];
    const float* b1   = (const float*)d_in[7];
    const float* W_ih = (const float*)d_in[8];
    const float* W_hh = (const float*)d_in[9];
    const float* b_ih = (const float*)d_in[10];
    const float* b_hh = (const float*)d_in[11];
    const float* gamma = (const float*)d_in[12];
    const float* beta  = (const float*)d_in[13];
    const float* We1  = (const float*)d_in[14];
    const float* be1  = (const float*)d_in[15];
    const float* We2  = (const float*)d_in[16];
    const float* be2  = (const float*)d_in[17];
    float* out = (float*)d_out;

    char* ws = (char*)d_ws;
    size_t off = 0;
    auto alloc = [&](size_t bytes) -> void* {
        void* p = ws + off;
        off += (bytes + 255) & ~(size_t)255;
        return p;
    };
    // ---- persistent ----
    int*   row_ptr = (int*)  alloc((size_t)T_SNAP * (N_NODES + 1) * 4);
    uint2* colval  = (uint2*)alloc((size_t)T_SNAP * E_EDGES * 8);
    u16*   W0_bf   = (u16*)  alloc((size_t)N_NODES * NHID * 2);
    u16*   W1t     = (u16*)  alloc((size_t)NOUT * NHID * 2);
    u16*   We1T    = (u16*)  alloc((size_t)NHID_E * 256 * 2);
    u16*   BgB     = (u16*)  alloc((size_t)512 * 256 * 2);
    float* bgbB    = (float*)alloc(512 * 4);
    float* h       = (float*)alloc((size_t)N_NODES * HDIM * 4);
    float* stats   = (float*)alloc(256 * 4);
    int*   bcnt    = (int*)  alloc((size_t)T_SNAP * NBUCK * 4);
    int*   bbase   = (int*)  alloc((size_t)T_SNAP * NBUCK * 4);
    int*   ovf_cnt = (int*)  alloc(256);
    size_t mark = off;

    // ---- union region: CSR phase ----
    off = mark;
    uint2* staging = (uint2*)alloc((size_t)T_SNAP * NBUCK * BCAP * 8);
    uint4* ovf     = (uint4*)alloc((size_t)T_SNAP * E_EDGES * 16);
    size_t csr_end = off;

    // ---- union region: compute phase (BT adaptive 8 -> 4) ----
    int BT = 8;
    u16 *X0_b, *Y_b, *X2_all;
    size_t comp_end;
    for (;;) {
        off = mark;
        X0_b   = (u16*)alloc((size_t)BT * N_NODES * NHID * 2);
        Y_b    = (u16*)alloc((size_t)BT * N_NODES * NOUT * 2);
        X2_all = (u16*)alloc((size_t)T_SNAP * N_NODES * NOUT * 2);
        comp_end = off;
        if (comp_end <= ws_size || BT == 4) break;
        BT >>= 1;
    }

    // ---- union region: post phase ----
    off = mark;
    u16* emb = (u16*)alloc((size_t)N_NODES * HDIM * 2);
    u16* P   = (u16*)alloc((size_t)N_NODES * NHID_E * 2);
    u16* Q   = (u16*)alloc((size_t)N_NODES * NHID_E * 2);
    size_t post_end = off;

    size_t need = csr_end;
    if (comp_end > need) need = comp_end;
    if (post_end > need) need = post_end;
    if (need > ws_size) return;   // visible failure instead of corruption

    hipMemsetAsync(bcnt,    0, (size_t)T_SNAP * NBUCK * 4, stream);
    hipMemsetAsync(ovf_cnt, 0, 256, stream);
    hipMemsetAsync(stats,   0, 256 * 4, stream);

    // ---- CSR build v2 ----
    dim3 p1g((E_EDGES + P1CHUNK - 1) / P1CHUNK, T_SNAP);
    k_p1   <<<p1g, 256, 0, stream>>>(adj_rows, adj_cols, adj_vals, bcnt, staging, ovf, ovf_cnt);
    k_bscan<<<1, 256, 0, stream>>>(bcnt, bbase, row_ptr);
    k_p2   <<<dim3(NBUCK, T_SNAP), 256, 0, stream>>>(bcnt, bbase, staging, ovf, ovf_cnt,
                                                     colval, row_ptr);

    // ---- weight conversions ----
    k_cvt      <<<(N_NODES * NHID / 4 + 255) / 256, 256, 0, stream>>>(W0, W0_bf, N_NODES * NHID / 4);
    k_tcvt     <<<(NHID * NOUT + 255) / 256,  256, 0, stream>>>(W1, W1t, NHID, NOUT);
    k_tcvt     <<<(256 * NHID_E + 255) / 256, 256, 0, stream>>>(We1, We1T, 256, NHID_E);
    k_build_bg <<<(512 * 256 + 255) / 256, 256, 0, stream>>>(W_ih, W_hh, BgB);
    k_build_bgb<<<2, 256, 0, stream>>>(b_ih, b_hh, bgbB);

    // ---- batched GCN: layer0 spmm -> X0@W1 -> layer1 spmm -> X2_all ----
    for (int g = 0; g < T_SNAP; g += BT) {
        k_spmm0<true><<<dim3(N_NODES / 4, BT), 256, 0, stream>>>(
            row_ptr, colval, g, W0_bf, b0, X0_b);
        int M = BT * N_NODES;
        k_mgemm<8, false><<<dim3(1, (M + 63) / 64), 256, 0, stream>>>(
            X0_b, W1t, NHID, nullptr, Y_b, NOUT, M);
        k_spmm1<false><<<dim3(N_NODES / 4, BT), 256, 0, stream>>>(
            row_ptr, colval, g, Y_b, (size_t)N_NODES * NOUT, b1,
            X2_all + (size_t)g * N_NODES * NOUT);
    }

    // ---- GRU: all 16 steps fused, Bg in VGPRs, 313 blocks (r12 geometry) ----
    k_gru_fused2<<<(N_NODES + 63) / 64, 512, 0, stream>>>(X2_all, BgB, bgbB, h);

    // ---- BatchNorm ----
    k_bnstats<<<100, 128, 0, stream>>>(h, stats);
    k_bnapply<<<(N_NODES * HDIM + 255) / 256, 256, 0, stream>>>(h, stats, gamma, beta, emb);

    // ---- Edge MLP precompute + predictor ----
    k_mgemm<4, true><<<dim3(2, (N_NODES + 63) / 64), 256, 0, stream>>>(
        emb, We1T, 256, be1, P, NHID_E, N_NODES);
    k_mgemm<4, false><<<dim3(2, (N_NODES + 63) / 64), 256, 0, stream>>>(
        emb, We1T + 128, 256, nullptr, Q, NHID_E, N_NODES);
    k_edge<<<(EP_EDGES + 3) / 4, 256, 0, stream>>>(edges, P, Q, We2, be2, out);
}

// Round 15
// 877.332 us; speedup vs baseline: 1.2875x; 1.0149x over previous
//
#include <hip/hip_runtime.h>
#include <math.h>

#define N_NODES 20000
#define NHID    256
#define NOUT    128
#define HDIM    128
#define NHID_E  256
#define T_SNAP  16
#define E_EDGES 320000
#define EP_EDGES 100000
#define BN_EPS  1e-5f

#define BROWS 128                    // rows per bucket
#define NBUCK 157                    // ceil(N_NODES / BROWS)
#define BCAP  4096                   // staging capacity per bucket
#define P1CHUNK 2048                 // edges per k_p1 block (25KB LDS -> 6 blk/CU)

typedef unsigned short u16;
typedef __attribute__((ext_vector_type(8))) short bf16x8;
typedef __attribute__((ext_vector_type(8))) unsigned short u16x8;
typedef __attribute__((ext_vector_type(4))) float f32x4;

__device__ __forceinline__ u16 f2b(float f) {
    unsigned u = __float_as_uint(f);
    u += 0x7FFFu + ((u >> 16) & 1u);
    return (u16)(u >> 16);
}
__device__ __forceinline__ float b2f(u16 s) { return __uint_as_float(((unsigned)s) << 16); }

// ---- fast transcendentals (v_exp_f32 / v_rcp_f32), guarded ----
__device__ __forceinline__ float fexp2(float x) {
#if __has_builtin(__builtin_amdgcn_exp2f)
    return __builtin_amdgcn_exp2f(x);
#else
    return exp2f(x);
#endif
}
__device__ __forceinline__ float frcp(float x) {
#if __has_builtin(__builtin_amdgcn_rcpf)
    return __builtin_amdgcn_rcpf(x);
#else
    return 1.f / x;
#endif
}
__device__ __forceinline__ float fsig(float x) {
    return frcp(1.f + fexp2(x * -1.4426950408889634f));
}
__device__ __forceinline__ float ftanh(float x) {
    float t = fexp2(x * 2.8853900817779268f);
    return 1.f - 2.f * frcp(t + 1.f);
}

// ---- bf16 dot2 path (guarded; falls back to shl+fma if builtin absent) ----
#if __has_builtin(__builtin_amdgcn_fdot2_f32_bf16)
#define HAVE_DOT2 1
typedef __attribute__((ext_vector_type(2))) __bf16 bf2v;
__device__ __forceinline__ float dot2b(unsigned x, unsigned v, float acc) {
    return __builtin_amdgcn_fdot2_f32_bf16(
        __builtin_bit_cast(bf2v, x), __builtin_bit_cast(bf2v, v), acc, false);
}
__device__ __forceinline__ unsigned pack_lo(unsigned a, unsigned b) {
#if __has_builtin(__builtin_amdgcn_perm)
    return __builtin_amdgcn_perm(a, b, 0x01000504u);   // (a.e0 | b.e0<<16)
#else
    return (a & 0xFFFFu) | (b << 16);
#endif
}
__device__ __forceinline__ unsigned pack_hi(unsigned a, unsigned b) {
#if __has_builtin(__builtin_amdgcn_perm)
    return __builtin_amdgcn_perm(a, b, 0x03020706u);   // (a.e1 | b.e1<<16)
#else
    return (a >> 16) | (b & 0xFFFF0000u);
#endif
}
#else
#define HAVE_DOT2 0
#endif

// ---------------------------------------------------------------------------
// CSR build v2, phase 1: block-local counting sort by bucket, append runs.
// ---------------------------------------------------------------------------
__global__ __launch_bounds__(256) void k_p1(const int* __restrict__ rows,
        const int* __restrict__ cols, const float* __restrict__ vals,
        int* __restrict__ bcnt, uint2* __restrict__ staging,
        uint4* __restrict__ ovf, int* __restrict__ ovf_cnt) {
    int t = blockIdx.y;
    int base = blockIdx.x * P1CHUNK;
    int tid = threadIdx.x;
    __shared__ int hist[256], sc[256], excl[256], cursor[256], gbase[256];
    __shared__ uint2 ebuf[P1CHUNK];
    __shared__ u16 ebuck[P1CHUNK];
    hist[tid] = 0;
    __syncthreads();
    const int*   rt = rows + (size_t)t * E_EDGES;
    const int*   ct = cols + (size_t)t * E_EDGES;
    const float* vt = vals + (size_t)t * E_EDGES;
    #pragma unroll
    for (int k = 0; k < P1CHUNK / 256; ++k) {
        int i = base + k * 256 + tid;
        if (i < E_EDGES) atomicAdd(&hist[rt[i] >> 7], 1);
    }
    __syncthreads();
    sc[tid] = hist[tid];
    __syncthreads();
    for (int off = 1; off < 256; off <<= 1) {
        int add = (tid >= off) ? sc[tid - off] : 0;
        __syncthreads();
        sc[tid] += add;
        __syncthreads();
    }
    excl[tid]   = sc[tid] - hist[tid];
    cursor[tid] = sc[tid] - hist[tid];
    __syncthreads();
    #pragma unroll
    for (int k = 0; k < P1CHUNK / 256; ++k) {
        int i = base + k * 256 + tid;
        if (i < E_EDGES) {
            int r = rt[i];
            int b = r >> 7;
            int s = atomicAdd(&cursor[b], 1);
            uint2 e;
            e.x = (unsigned)ct[i] | ((unsigned)(r & 127) << 15);
            e.y = __float_as_uint(vt[i]);
            ebuf[s]  = e;
            ebuck[s] = (u16)b;
        }
    }
    __syncthreads();
    if (hist[tid] > 0) gbase[tid] = atomicAdd(&bcnt[t * NBUCK + tid], hist[tid]);
    __syncthreads();
    int nvalid = min(P1CHUNK, E_EDGES - base);
    for (int s = tid; s < nvalid; s += 256) {
        int b = ebuck[s];
        int g = gbase[b] + (s - excl[b]);
        if (g < BCAP) {
            staging[((size_t)t * NBUCK + b) * BCAP + g] = ebuf[s];
        } else {
            int o = atomicAdd(ovf_cnt, 1);
            uint4 e4; e4.x = (unsigned)(t * NBUCK + b); e4.y = ebuf[s].x; e4.z = ebuf[s].y; e4.w = 0;
            ovf[o] = e4;
        }
    }
}

// phase 2a: exclusive scan of all bucket counts (2512 values), one block
__global__ void k_bscan(const int* __restrict__ bcnt, int* __restrict__ bbase,
                        int* __restrict__ row_ptr) {
    __shared__ int sh[256];
    __shared__ int carry;
    int tid = threadIdx.x;
    if (tid == 0) carry = 0;
    __syncthreads();
    for (int b0 = 0; b0 < T_SNAP * NBUCK; b0 += 256) {
        int i = b0 + tid;
        int v = (i < T_SNAP * NBUCK) ? bcnt[i] : 0;
        sh[tid] = v;
        __syncthreads();
        for (int off = 1; off < 256; off <<= 1) {
            int add = (tid >= off) ? sh[tid - off] : 0;
            __syncthreads();
            sh[tid] += add;
            __syncthreads();
        }
        if (i < T_SNAP * NBUCK) bbase[i] = carry + sh[tid] - v;
        __syncthreads();
        if (tid == 255) carry += sh[255];
        __syncthreads();
    }
    if (tid < T_SNAP) row_ptr[tid * (N_NODES + 1) + N_NODES] = E_EDGES;
}

// phase 2b: per-bucket row sort -> row_ptr + final colval
__global__ __launch_bounds__(256) void k_p2(const int* __restrict__ bcnt,
        const int* __restrict__ bbase, const uint2* __restrict__ staging,
        const uint4* __restrict__ ovf, const int* __restrict__ ovf_cnt,
        uint2* __restrict__ colval, int* __restrict__ row_ptr) {
    int b = blockIdx.x, t = blockIdx.y, tid = threadIdx.x;
    int idx = t * NBUCK + b;
    int cnt = bcnt[idx];
    int gb  = bbase[idx];
    __shared__ int hist[BROWS], cursor[BROWS], sc[BROWS];
    if (tid < BROWS) hist[tid] = 0;
    __syncthreads();
    int staged = min(cnt, BCAP);
    const uint2* st = staging + (size_t)idx * BCAP;
    for (int s = tid; s < staged; s += 256)
        atomicAdd(&hist[st[s].x >> 15], 1);
    int nov = (cnt > staged) ? *ovf_cnt : 0;
    for (int o = tid; o < nov; o += 256) {
        uint4 e = ovf[o];
        if ((int)e.x == idx) atomicAdd(&hist[(e.y >> 15) & 127], 1);
    }
    __syncthreads();
    if (tid < BROWS) sc[tid] = hist[tid];
    __syncthreads();
    for (int off = 1; off < BROWS; off <<= 1) {
        int add = (tid < BROWS && tid >= off) ? sc[tid - off] : 0;
        __syncthreads();
        if (tid < BROWS) sc[tid] += add;
        __syncthreads();
    }
    if (tid < BROWS) {
        int ex = sc[tid] - hist[tid];
        cursor[tid] = ex;
        int row = b * BROWS + tid;
        if (row < N_NODES)
            row_ptr[t * (N_NODES + 1) + row] = gb - t * E_EDGES + ex;
    }
    __syncthreads();
    for (int s = tid; s < staged; s += 256) {
        uint2 e = st[s];
        int rl = e.x >> 15;
        int pos = atomicAdd(&cursor[rl], 1);
        uint2 o2; o2.x = e.x & 0x7FFF; o2.y = e.y;
        colval[(size_t)gb + pos] = o2;
    }
    for (int o = tid; o < nov; o += 256) {
        uint4 e = ovf[o];
        if ((int)e.x == idx) {
            int rl = (e.y >> 15) & 127;
            int pos = atomicAdd(&cursor[rl], 1);
            uint2 o2; o2.x = e.y & 0x7FFF; o2.y = e.z;
            colval[(size_t)gb + pos] = o2;
        }
    }
}

// ---------------------------------------------------------------------------
// Conversions / weight builders
// ---------------------------------------------------------------------------
__global__ void k_cvt(const float* __restrict__ in, u16* __restrict__ out, int n4) {
    int i = blockIdx.x * 256 + threadIdx.x;
    if (i < n4) {
        float4 v = ((const float4*)in)[i];
        ushort4 o;
        o.x = f2b(v.x); o.y = f2b(v.y); o.z = f2b(v.z); o.w = f2b(v.w);
        ((ushort4*)out)[i] = o;
    }
}

__global__ void k_tcvt(const float* __restrict__ in, u16* __restrict__ out, int Kr, int Nc) {
    int i = blockIdx.x * 256 + threadIdx.x;
    if (i < Kr * Nc) {
        int k = i / Nc, n = i - k * Nc;
        out[(size_t)n * Kr + k] = f2b(in[i]);
    }
}

// 512-col interleave over concat(x,h)
__global__ void k_build_bg(const float* __restrict__ Wih, const float* __restrict__ Whh,
                           u16* __restrict__ Bg) {
    int i = blockIdx.x * 256 + threadIdx.x;
    if (i >= 512 * 256) return;
    int rr = i >> 8, k = i & 255;
    int c = rr >> 4, u = rr & 15, g = c & 3, jj = ((c >> 2) << 4) + u;
    float v;
    if (g == 0)      v = (k < 128) ? Wih[(size_t)jj * 128 + k]         : Whh[(size_t)jj * 128 + k - 128];
    else if (g == 1) v = (k < 128) ? Wih[(size_t)(128 + jj) * 128 + k] : Whh[(size_t)(128 + jj) * 128 + k - 128];
    else if (g == 2) v = (k < 128) ? Wih[(size_t)(256 + jj) * 128 + k] : 0.f;
    else             v = (k < 128) ? 0.f : Whh[(size_t)(256 + jj) * 128 + k - 128];
    Bg[i] = f2b(v);
}

__global__ void k_build_bgb(const float* __restrict__ bih, const float* __restrict__ bhh,
                            float* __restrict__ bgb) {
    int rr = blockIdx.x * 256 + threadIdx.x;
    if (rr >= 512) return;
    int c = rr >> 4, u = rr & 15, g = c & 3, jj = ((c >> 2) << 4) + u;
    float v;
    if (g == 0)      v = bih[jj] + bhh[jj];
    else if (g == 1) v = bih[128 + jj] + bhh[128 + jj];
    else if (g == 2) v = bih[256 + jj];
    else             v = bhh[256 + jj];
    bgb[rr] = v;
}

// ---------------------------------------------------------------------------
// SpMM layer0 (D=256): one row per wave, half-wave per edge stream, 2 streams
// (r7 version — at the random-gather memory-path roofline).
// ---------------------------------------------------------------------------
template<bool RELU>
__global__ __launch_bounds__(256) void k_spmm0(
        const int* __restrict__ rp_all, const uint2* __restrict__ cv_all,
        int t0, const u16* __restrict__ X,
        const float* __restrict__ bias, u16* __restrict__ Out) {
    int lane = threadIdx.x & 63;
    int row = blockIdx.x * 4 + (threadIdx.x >> 6);
    int tl = blockIdx.y, t = t0 + tl;
    const int*   rp = rp_all + (size_t)t * (N_NODES + 1);
    const uint2* cv = cv_all + (size_t)t * E_EDGES;
    int hw = lane >> 5, l = lane & 31;
    int s = rp[row], e = rp[row + 1];
    int k = s + hw;
    uint2 a0 = make_uint2(0u, 0u), a1 = make_uint2(0u, 0u);
    if (k < e)     a0 = cv[k];
    if (k + 2 < e) a1 = cv[k + 2];
#if HAVE_DOT2
    float acc[8] = {};
    for (; k < e; k += 4) {
        uint2 c0 = a0, c1 = a1;
        bool ok1 = (k + 2) < e;
        int e1 = e - 1;
        a0 = cv[min(k + 4, e1)];
        a1 = cv[min(k + 6, e1)];
        unsigned col1 = ok1 ? c1.x : c0.x;
        float va1f = ok1 ? __uint_as_float(c1.y) : 0.f;
        unsigned vv = (unsigned)f2b(__uint_as_float(c0.y)) | ((unsigned)f2b(va1f) << 16);
        uint4 x0 = *(const uint4*)(X + (size_t)c0.x * NHID + l * 8);
        uint4 x1 = *(const uint4*)(X + (size_t)col1 * NHID + l * 8);
        acc[0] = dot2b(pack_lo(x0.x, x1.x), vv, acc[0]);
        acc[1] = dot2b(pack_hi(x0.x, x1.x), vv, acc[1]);
        acc[2] = dot2b(pack_lo(x0.y, x1.y), vv, acc[2]);
        acc[3] = dot2b(pack_hi(x0.y, x1.y), vv, acc[3]);
        acc[4] = dot2b(pack_lo(x0.z, x1.z), vv, acc[4]);
        acc[5] = dot2b(pack_hi(x0.z, x1.z), vv, acc[5]);
        acc[6] = dot2b(pack_lo(x0.w, x1.w), vv, acc[6]);
        acc[7] = dot2b(pack_hi(x0.w, x1.w), vv, acc[7]);
    }
    #pragma unroll
    for (int i = 0; i < 8; ++i) {
        float v = acc[i];
        v += __shfl_xor(v, 32);
        v += bias[l * 8 + i];
        acc[i] = RELU ? fmaxf(v, 0.f) : v;
    }
    float* accw = acc;
#else
    float acc0[8] = {}, acc1[8] = {};
    for (; k < e; k += 4) {
        uint2 c0 = a0, c1 = a1;
        bool ok1 = (k + 2) < e;
        int e1 = e - 1;
        a0 = cv[min(k + 4, e1)];
        a1 = cv[min(k + 6, e1)];
        float va0 = __uint_as_float(c0.y);
        float va1 = ok1 ? __uint_as_float(c1.y) : 0.f;
        unsigned col1 = ok1 ? c1.x : c0.x;
        u16x8 x0 = *(const u16x8*)(X + (size_t)c0.x * NHID + l * 8);
        u16x8 x1 = *(const u16x8*)(X + (size_t)col1 * NHID + l * 8);
        #pragma unroll
        for (int i = 0; i < 8; ++i) {
            acc0[i] = fmaf(va0, b2f(x0[i]), acc0[i]);
            acc1[i] = fmaf(va1, b2f(x1[i]), acc1[i]);
        }
    }
    #pragma unroll
    for (int i = 0; i < 8; ++i) {
        float v = acc0[i] + acc1[i];
        v += __shfl_xor(v, 32);
        v += bias[l * 8 + i];
        acc0[i] = RELU ? fmaxf(v, 0.f) : v;
    }
    float* accw = acc0;
#endif
    if (hw == 0) {
        u16x8 o;
        #pragma unroll
        for (int i = 0; i < 8; ++i) o[i] = f2b(accw[i]);
        *(u16x8*)(Out + ((size_t)tl * N_NODES + row) * NHID + l * 8) = o;
    }
}

// ---------------------------------------------------------------------------
// SpMM layer1 (D=128): quarter-wave per edge stream, 2 streams (r7 version).
// ---------------------------------------------------------------------------
template<bool RELU>
__global__ __launch_bounds__(256) void k_spmm1(
        const int* __restrict__ rp_all, const uint2* __restrict__ cv_all,
        int t0, const u16* __restrict__ X, size_t xtstride,
        const float* __restrict__ bias, u16* __restrict__ Out) {
    int lane = threadIdx.x & 63;
    int row = blockIdx.x * 4 + (threadIdx.x >> 6);
    int tl = blockIdx.y, t = t0 + tl;
    const int*   rp = rp_all + (size_t)t * (N_NODES + 1);
    const uint2* cv = cv_all + (size_t)t * E_EDGES;
    const u16*   Xt = X + xtstride * tl;
    int qw = lane >> 4, l = lane & 15;
    int s = rp[row], e = rp[row + 1];
    int k = s + qw;
    uint2 a0 = make_uint2(0u, 0u), a1 = make_uint2(0u, 0u);
    if (k < e)     a0 = cv[k];
    if (k + 4 < e) a1 = cv[k + 4];
#if HAVE_DOT2
    float acc[8] = {};
    for (; k < e; k += 8) {
        uint2 c0 = a0, c1 = a1;
        bool ok1 = (k + 4) < e;
        int e1 = e - 1;
        a0 = cv[min(k + 8, e1)];
        a1 = cv[min(k + 12, e1)];
        unsigned col1 = ok1 ? c1.x : c0.x;
        float va1f = ok1 ? __uint_as_float(c1.y) : 0.f;
        unsigned vv = (unsigned)f2b(__uint_as_float(c0.y)) | ((unsigned)f2b(va1f) << 16);
        uint4 x0 = *(const uint4*)(Xt + (size_t)c0.x * NOUT + l * 8);
        uint4 x1 = *(const uint4*)(Xt + (size_t)col1 * NOUT + l * 8);
        acc[0] = dot2b(pack_lo(x0.x, x1.x), vv, acc[0]);
        acc[1] = dot2b(pack_hi(x0.x, x1.x), vv, acc[1]);
        acc[2] = dot2b(pack_lo(x0.y, x1.y), vv, acc[2]);
        acc[3] = dot2b(pack_hi(x0.y, x1.y), vv, acc[3]);
        acc[4] = dot2b(pack_lo(x0.z, x1.z), vv, acc[4]);
        acc[5] = dot2b(pack_hi(x0.z, x1.z), vv, acc[5]);
        acc[6] = dot2b(pack_lo(x0.w, x1.w), vv, acc[6]);
        acc[7] = dot2b(pack_hi(x0.w, x1.w), vv, acc[7]);
    }
    #pragma unroll
    for (int i = 0; i < 8; ++i) {
        float v = acc[i];
        v += __shfl_xor(v, 32);
        v += __shfl_xor(v, 16);
        v += bias[l * 8 + i];
        acc[i] = RELU ? fmaxf(v, 0.f) : v;
    }
    float* accw = acc;
#else
    float acc0[8] = {}, acc1[8] = {};
    for (; k < e; k += 8) {
        uint2 c0 = a0, c1 = a1;
        bool ok1 = (k + 4) < e;
        int e1 = e - 1;
        a0 = cv[min(k + 8, e1)];
        a1 = cv[min(k + 12, e1)];
        float va0 = __uint_as_float(c0.y);
        float va1 = ok1 ? __uint_as_float(c1.y) : 0.f;
        unsigned col1 = ok1 ? c1.x : c0.x;
        u16x8 x0 = *(const u16x8*)(Xt + (size_t)c0.x * NOUT + l * 8);
        u16x8 x1 = *(const u16x8*)(Xt + (size_t)col1 * NOUT + l * 8);
        #pragma unroll
        for (int i = 0; i < 8; ++i) {
            acc0[i] = fmaf(va0, b2f(x0[i]), acc0[i]);
            acc1[i] = fmaf(va1, b2f(x1[i]), acc1[i]);
        }
    }
    #pragma unroll
    for (int i = 0; i < 8; ++i) {
        float v = acc0[i] + acc1[i];
        v += __shfl_xor(v, 32);
        v += __shfl_xor(v, 16);
        v += bias[l * 8 + i];
        acc0[i] = RELU ? fmaxf(v, 0.f) : v;
    }
    float* accw = acc0;
#endif
    if (qw == 0) {
        u16x8 o;
        #pragma unroll
        for (int i = 0; i < 8; ++i) o[i] = f2b(accw[i]);
        *(u16x8*)(Out + ((size_t)tl * N_NODES + row) * NOUT + l * 8) = o;
    }
}

// ---------------------------------------------------------------------------
// bf16 MFMA GEMM: C[M,Nc] = A[M,K] @ B^T (+bias), out bf16. tile 64x128.
// ---------------------------------------------------------------------------
template<int KC, bool BIAS>
__global__ __launch_bounds__(256) void k_mgemm(
        const u16* __restrict__ A, const u16* __restrict__ B, int ldb,
        const float* __restrict__ bias, u16* __restrict__ C, int ldc, int M) {
    constexpr int K = KC * 32;
    __shared__ bf16x8 frag[8 * KC * 64];
    int tid = threadIdx.x, lane = tid & 63, wave = tid >> 6;
    int m0 = blockIdx.y * 64, n0 = blockIdx.x * 128;

    for (int f = wave; f < 8 * KC; f += 4) {
        int nl = f / KC, kc = f % KC;
        frag[f * 64 + lane] = *(const bf16x8*)(B + (size_t)(n0 + nl * 16 + (lane & 15)) * ldb
                                               + kc * 32 + ((lane >> 4) << 3));
    }
    __syncthreads();

    int arow = m0 + wave * 16 + (lane & 15);
    bool rowok = arow < M;
    const u16* ap = A + (size_t)arow * K + ((lane >> 4) << 3);
    bf16x8 zf = {0, 0, 0, 0, 0, 0, 0, 0};
    bf16x8 af[KC];
    #pragma unroll
    for (int kc = 0; kc < KC; ++kc)
        af[kc] = rowok ? *(const bf16x8*)(ap + kc * 32) : zf;

    f32x4 acc[8] = {};
    #pragma unroll
    for (int kc = 0; kc < KC; ++kc)
        #pragma unroll
        for (int nl = 0; nl < 8; ++nl)
            acc[nl] = __builtin_amdgcn_mfma_f32_16x16x32_bf16(
                af[kc], frag[(nl * KC + kc) * 64 + lane], acc[nl], 0, 0, 0);

    int r0 = m0 + wave * 16 + ((lane >> 4) << 2);
    #pragma unroll
    for (int nl = 0; nl < 8; ++nl) {
        int col = n0 + nl * 16 + (lane & 15);
        float bv = BIAS ? bias[col] : 0.f;
        #pragma unroll
        for (int r = 0; r < 4; ++r) {
            int row = r0 + r;
            if (row < M) C[(size_t)row * ldc + col] = f2b(acc[nl][r] + bv);
        }
    }
}

// ---------------------------------------------------------------------------
// Fused all-16-step GRU: wave-specialized, Bg resident in VGPRs.
// Block = 32 nodes, 512 thr / 8 waves, 625 blocks (N = 625*32 exactly ->
// no bounds checks), launch_bounds(512,2) -- the PROVEN bound (r12/r14:
// VGPR 116, no spill). 2.4 blocks/CU for double the TLP of the 64-node
// version. Wave w: quadrant q=w>>1, half hb=w&1; its 4 nl-tiles are the
// gates (r,z,i,n) of hidden slice jj=(2q+hb)*16+u. h bf16 double-buffered
// in padded LDS; h fp32 in regs. Fast hw sigmoid/tanh. One barrier/step.
// ---------------------------------------------------------------------------
__global__ __launch_bounds__(512, 2) void k_gru_fused2(
        const u16* __restrict__ X2_all, const u16* __restrict__ Bg,
        const float* __restrict__ bgb, float* __restrict__ H) {
    __shared__ u16 hbuf[2][32][132];           // 2 x 8.4 KB, +4 pad
    int tid = threadIdx.x, lane = tid & 63, wave = tid >> 6;
    int q = wave >> 1, hb = wave & 1;
    int u = lane & 15, kgrp = lane >> 4;       // kgrp 0..3
    int m0 = blockIdx.x * 32;
    int jj = (2 * q + hb) * 16 + u;            // this wave's hidden slice col

    // ---- load this wave's 32 B-fragments into registers (once) ----
    bf16x8 bfrag[4][8];
    #pragma unroll
    for (int g = 0; g < 4; ++g)
        #pragma unroll
        for (int kc = 0; kc < 8; ++kc)
            bfrag[g][kc] = *(const bf16x8*)(Bg
                + (size_t)(q * 128 + (4 * hb + g) * 16 + u) * 256
                + kc * 32 + kgrp * 8);

    float bR = bgb[q * 128 + (4 * hb + 0) * 16 + u];
    float bZ = bgb[q * 128 + (4 * hb + 1) * 16 + u];
    float bI = bgb[q * 128 + (4 * hb + 2) * 16 + u];
    float bH = bgb[q * 128 + (4 * hb + 3) * 16 + u];

    for (int i = tid; i < 32 * 132; i += 512) ((u16*)hbuf[0])[i] = 0;

    float hstate[2][4] = {};                   // [tile][r]
    __syncthreads();

    for (int t = 0; t < T_SNAP; ++t) {
        const u16* X2t = X2_all + (size_t)t * N_NODES * NOUT;
        int rb = t & 1, wb = rb ^ 1;
        #pragma unroll
        for (int tile = 0; tile < 2; ++tile) {
            int arow = m0 + tile * 16 + u;
            bf16x8 afx[4], afh[4];
            const u16* a1 = X2t + (size_t)arow * 128 + kgrp * 8;
            #pragma unroll
            for (int kc = 0; kc < 4; ++kc)
                afx[kc] = *(const bf16x8*)(a1 + kc * 32);
            #pragma unroll
            for (int kc = 0; kc < 4; ++kc)
                afh[kc] = *(const bf16x8*)&hbuf[rb][tile * 16 + u][kc * 32 + kgrp * 8];

            f32x4 acc[4] = {};
            #pragma unroll
            for (int kc = 0; kc < 4; ++kc)
                #pragma unroll
                for (int g = 0; g < 4; ++g)
                    acc[g] = __builtin_amdgcn_mfma_f32_16x16x32_bf16(
                        afx[kc], bfrag[g][kc], acc[g], 0, 0, 0);
            #pragma unroll
            for (int kc = 0; kc < 4; ++kc)
                #pragma unroll
                for (int g = 0; g < 4; ++g)
                    acc[g] = __builtin_amdgcn_mfma_f32_16x16x32_bf16(
                        afh[kc], bfrag[g][4 + kc], acc[g], 0, 0, 0);

            #pragma unroll
            for (int r = 0; r < 4; ++r) {
                int lrow = tile * 16 + kgrp * 4 + r;
                float rg = fsig(acc[0][r] + bR);
                float zg = fsig(acc[1][r] + bZ);
                float ng = ftanh(acc[2][r] + bI + rg * (acc[3][r] + bH));
                float hn = (1.f - zg) * ng + zg * hstate[tile][r];
                hstate[tile][r] = hn;
                hbuf[wb][lrow][jj] = f2b(hn);
            }
        }
        __syncthreads();   // wb complete before next step reads it
    }
    #pragma unroll
    for (int tile = 0; tile < 2; ++tile)
        #pragma unroll
        for (int r = 0; r < 4; ++r) {
            int row = m0 + tile * 16 + kgrp * 4 + r;
            H[(size_t)row * HDIM + jj] = hstate[tile][r];
        }
}

// ---------------------------------------------------------------------------
// BatchNorm
// ---------------------------------------------------------------------------
__global__ void k_bnstats(const float* __restrict__ h, float* __restrict__ stats) {
    int j = threadIdx.x;
    int r0 = blockIdx.x * 200;
    float s = 0.f, sq = 0.f;
    for (int r = r0; r < r0 + 200; ++r) {
        float v = h[(size_t)r * HDIM + j];
        s += v; sq += v * v;
    }
    atomicAdd(&stats[j], s);
    atomicAdd(&stats[128 + j], sq);
}

__global__ void k_bnapply(const float* __restrict__ h, const float* __restrict__ stats,
                          const float* __restrict__ gamma, const float* __restrict__ beta,
                          u16* __restrict__ emb) {
    int i = blockIdx.x * 256 + threadIdx.x;
    if (i >= N_NODES * HDIM) return;
    int j = i & 127;
    float mean = stats[j] * (1.f / N_NODES);
    float var  = stats[128 + j] * (1.f / N_NODES) - mean * mean;
    emb[i] = f2b((h[i] - mean) * rsqrtf(var + BN_EPS) * gamma[j] + beta[j]);
}

// ---------------------------------------------------------------------------
// Edge predictor
// ---------------------------------------------------------------------------
__global__ __launch_bounds__(256) void k_edge(const int* __restrict__ edges,
        const u16* __restrict__ P, const u16* __restrict__ Q,
        const float* __restrict__ We2, const float* __restrict__ be2,
        float* __restrict__ out) {
    int e = blockIdx.x * 4 + (threadIdx.x >> 6);
    int lane = threadIdx.x & 63;
    if (e >= EP_EDGES) return;
    int u = edges[e];
    int v = edges[EP_EDGES + e];
    ushort4 pv = *(const ushort4*)(P + (size_t)u * NHID_E + lane * 4);
    ushort4 qv = *(const ushort4*)(Q + (size_t)v * NHID_E + lane * 4);
    const float4* w = (const float4*)(We2 + lane * 8);
    float4 w0 = w[0], w1 = w[1];
    float h0 = fmaxf(b2f(pv.x) + b2f(qv.x), 0.f);
    float h1 = fmaxf(b2f(pv.y) + b2f(qv.y), 0.f);
    float h2 = fmaxf(b2f(pv.z) + b2f(qv.z), 0.f);
    float h3 = fmaxf(b2f(pv.w) + b2f(qv.w), 0.f);
    float l0 = h0 * w0.x + h1 * w0.z + h2 * w1.x + h3 * w1.z;
    float l1 = h0 * w0.y + h1 * w0.w + h2 * w1.y + h3 * w1.w;
    #pragma unroll
    for (int off = 32; off > 0; off >>= 1) {
        l0 += __shfl_down(l0, off);
        l1 += __shfl_down(l1, off);
    }
    if (lane == 0) {
        l0 += be2[0]; l1 += be2[1];
        float m = fmaxf(l0, l1);
        float lse = m + logf(expf(l0 - m) + expf(l1 - m));
        out[(size_t)e * 2 + 0] = l0 - lse;
        out[(size_t)e * 2 + 1] = l1 - lse;
    }
}

// ---------------------------------------------------------------------------
extern "C" void kernel_launch(void* const* d_in, const int* in_sizes, int n_in,
                              void* d_out, int out_size, void* d_ws, size_t ws_size,
                              hipStream_t stream) {
    const int*   adj_rows = (const int*)  d_in[0];
    const int*   adj_cols = (const int*)  d_in[1];
    const float* adj_vals = (const float*)d_in[2];
    const int*   edges    = (const int*)  d_in[3];
    const float* W0   = (const float*)d_in[4];
    const float* b0   = (const float*)d_in[5];
    const float* W1   = (const float*)d_in[6];
    const float* b1   = (const float*)d_in[7];
    const float* W_ih = (const float*)d_in[8];
    const float* W_hh = (const float*)d_in[9];
    const float* b_ih = (const float*)d_in[10];
    const float* b_hh = (const float*)d_in[11];
    const float* gamma = (const float*)d_in[12];
    const float* beta  = (const float*)d_in[13];
    const float* We1  = (const float*)d_in[14];
    const float* be1  = (const float*)d_in[15];
    const float* We2  = (const float*)d_in[16];
    const float* be2  = (const float*)d_in[17];
    float* out = (float*)d_out;

    char* ws = (char*)d_ws;
    size_t off = 0;
    auto alloc = [&](size_t bytes) -> void* {
        void* p = ws + off;
        off += (bytes + 255) & ~(size_t)255;
        return p;
    };
    // ---- persistent ----
    int*   row_ptr = (int*)  alloc((size_t)T_SNAP * (N_NODES + 1) * 4);
    uint2* colval  = (uint2*)alloc((size_t)T_SNAP * E_EDGES * 8);
    u16*   W0_bf   = (u16*)  alloc((size_t)N_NODES * NHID * 2);
    u16*   W1t     = (u16*)  alloc((size_t)NOUT * NHID * 2);
    u16*   We1T    = (u16*)  alloc((size_t)NHID_E * 256 * 2);
    u16*   BgB     = (u16*)  alloc((size_t)512 * 256 * 2);
    float* bgbB    = (float*)alloc(512 * 4);
    float* h       = (float*)alloc((size_t)N_NODES * HDIM * 4);
    float* stats   = (float*)alloc(256 * 4);
    int*   bcnt    = (int*)  alloc((size_t)T_SNAP * NBUCK * 4);
    int*   bbase   = (int*)  alloc((size_t)T_SNAP * NBUCK * 4);
    int*   ovf_cnt = (int*)  alloc(256);
    size_t mark = off;

    // ---- union region: CSR phase ----
    off = mark;
    uint2* staging = (uint2*)alloc((size_t)T_SNAP * NBUCK * BCAP * 8);
    uint4* ovf     = (uint4*)alloc((size_t)T_SNAP * E_EDGES * 16);
    size_t csr_end = off;

    // ---- union region: compute phase (BT adaptive 8 -> 4) ----
    int BT = 8;
    u16 *X0_b, *Y_b, *X2_all;
    size_t comp_end;
    for (;;) {
        off = mark;
        X0_b   = (u16*)alloc((size_t)BT * N_NODES * NHID * 2);
        Y_b    = (u16*)alloc((size_t)BT * N_NODES * NOUT * 2);
        X2_all = (u16*)alloc((size_t)T_SNAP * N_NODES * NOUT * 2);
        comp_end = off;
        if (comp_end <= ws_size || BT == 4) break;
        BT >>= 1;
    }

    // ---- union region: post phase ----
    off = mark;
    u16* emb = (u16*)alloc((size_t)N_NODES * HDIM * 2);
    u16* P   = (u16*)alloc((size_t)N_NODES * NHID_E * 2);
    u16* Q   = (u16*)alloc((size_t)N_NODES * NHID_E * 2);
    size_t post_end = off;

    size_t need = csr_end;
    if (comp_end > need) need = comp_end;
    if (post_end > need) need = post_end;
    if (need > ws_size) return;   // visible failure instead of corruption

    hipMemsetAsync(bcnt,    0, (size_t)T_SNAP * NBUCK * 4, stream);
    hipMemsetAsync(ovf_cnt, 0, 256, stream);
    hipMemsetAsync(stats,   0, 256 * 4, stream);

    // ---- CSR build v2 ----
    dim3 p1g((E_EDGES + P1CHUNK - 1) / P1CHUNK, T_SNAP);
    k_p1   <<<p1g, 256, 0, stream>>>(adj_rows, adj_cols, adj_vals, bcnt, staging, ovf, ovf_cnt);
    k_bscan<<<1, 256, 0, stream>>>(bcnt, bbase, row_ptr);
    k_p2   <<<dim3(NBUCK, T_SNAP), 256, 0, stream>>>(bcnt, bbase, staging, ovf, ovf_cnt,
                                                     colval, row_ptr);

    // ---- weight conversions ----
    k_cvt      <<<(N_NODES * NHID / 4 + 255) / 256, 256, 0, stream>>>(W0, W0_bf, N_NODES * NHID / 4);
    k_tcvt     <<<(NHID * NOUT + 255) / 256,  256, 0, stream>>>(W1, W1t, NHID, NOUT);
    k_tcvt     <<<(256 * NHID_E + 255) / 256, 256, 0, stream>>>(We1, We1T, 256, NHID_E);
    k_build_bg <<<(512 * 256 + 255) / 256, 256, 0, stream>>>(W_ih, W_hh, BgB);
    k_build_bgb<<<2, 256, 0, stream>>>(b_ih, b_hh, bgbB);

    // ---- batched GCN: layer0 spmm -> X0@W1 -> layer1 spmm -> X2_all ----
    for (int g = 0; g < T_SNAP; g += BT) {
        k_spmm0<true><<<dim3(N_NODES / 4, BT), 256, 0, stream>>>(
            row_ptr, colval, g, W0_bf, b0, X0_b);
        int M = BT * N_NODES;
        k_mgemm<8, false><<<dim3(1, (M + 63) / 64), 256, 0, stream>>>(
            X0_b, W1t, NHID, nullptr, Y_b, NOUT, M);
        k_spmm1<false><<<dim3(N_NODES / 4, BT), 256, 0, stream>>>(
            row_ptr, colval, g, Y_b, (size_t)N_NODES * NOUT, b1,
            X2_all + (size_t)g * N_NODES * NOUT);
    }

    // ---- GRU: all 16 steps fused, Bg in VGPRs, 625 blocks (32 nodes each) ----
    k_gru_fused2<<<N_NODES / 32, 512, 0, stream>>>(X2_all, BgB, bgbB, h);

    // ---- BatchNorm ----
    k_bnstats<<<100, 128, 0, stream>>>(h, stats);
    k_bnapply<<<(N_NODES * HDIM + 255) / 256, 256, 0, stream>>>(h, stats, gamma, beta, emb);

    // ---- Edge MLP precompute + predictor ----
    k_mgemm<4, true><<<dim3(2, (N_NODES + 63) / 64), 256, 0, stream>>>(
        emb, We1T, 256, be1, P, NHID_E, N_NODES);
    k_mgemm<4, false><<<dim3(2, (N_NODES + 63) / 64), 256, 0, stream>>>(
        emb, We1T + 128, 256, nullptr, Q, NHID_E, N_NODES);
    k_edge<<<(EP_EDGES + 3) / 4, 256, 0, stream>>>(edges, P, Q, We2, be2, out);
}

// Round 16
// 816.656 us; speedup vs baseline: 1.3832x; 1.0743x over previous
//
#include <hip/hip_runtime.h>
#include <math.h>

#define N_NODES 20000
#define NHID    256
#define NOUT    128
#define HDIM    128
#define NHID_E  256
#define T_SNAP  16
#define E_EDGES 320000
#define EP_EDGES 100000
#define BN_EPS  1e-5f

#define BROWS 128                    // rows per bucket
#define NBUCK 157                    // ceil(N_NODES / BROWS)
#define BCAP  4096                   // staging capacity per bucket
#define P1CHUNK 2048                 // edges per k_p1 block (25KB LDS -> 6 blk/CU)

typedef unsigned short u16;
typedef __attribute__((ext_vector_type(8))) short bf16x8;
typedef __attribute__((ext_vector_type(8))) unsigned short u16x8;
typedef __attribute__((ext_vector_type(4))) float f32x4;

__device__ __forceinline__ u16 f2b(float f) {
    unsigned u = __float_as_uint(f);
    u += 0x7FFFu + ((u >> 16) & 1u);
    return (u16)(u >> 16);
}
__device__ __forceinline__ float b2f(u16 s) { return __uint_as_float(((unsigned)s) << 16); }

// ---- fast transcendentals (v_exp_f32 / v_rcp_f32), guarded ----
__device__ __forceinline__ float fexp2(float x) {
#if __has_builtin(__builtin_amdgcn_exp2f)
    return __builtin_amdgcn_exp2f(x);
#else
    return exp2f(x);
#endif
}
__device__ __forceinline__ float frcp(float x) {
#if __has_builtin(__builtin_amdgcn_rcpf)
    return __builtin_amdgcn_rcpf(x);
#else
    return 1.f / x;
#endif
}
__device__ __forceinline__ float fsig(float x) {
    return frcp(1.f + fexp2(x * -1.4426950408889634f));
}
__device__ __forceinline__ float ftanh(float x) {
    float t = fexp2(x * 2.8853900817779268f);
    return 1.f - 2.f * frcp(t + 1.f);
}

// ---- bf16 dot2 path (guarded; falls back to shl+fma if builtin absent) ----
#if __has_builtin(__builtin_amdgcn_fdot2_f32_bf16)
#define HAVE_DOT2 1
typedef __attribute__((ext_vector_type(2))) __bf16 bf2v;
__device__ __forceinline__ float dot2b(unsigned x, unsigned v, float acc) {
    return __builtin_amdgcn_fdot2_f32_bf16(
        __builtin_bit_cast(bf2v, x), __builtin_bit_cast(bf2v, v), acc, false);
}
__device__ __forceinline__ unsigned pack_lo(unsigned a, unsigned b) {
#if __has_builtin(__builtin_amdgcn_perm)
    return __builtin_amdgcn_perm(a, b, 0x01000504u);   // (a.e0 | b.e0<<16)
#else
    return (a & 0xFFFFu) | (b << 16);
#endif
}
__device__ __forceinline__ unsigned pack_hi(unsigned a, unsigned b) {
#if __has_builtin(__builtin_amdgcn_perm)
    return __builtin_amdgcn_perm(a, b, 0x03020706u);   // (a.e1 | b.e1<<16)
#else
    return (a >> 16) | (b & 0xFFFF0000u);
#endif
}
#else
#define HAVE_DOT2 0
#endif

// ---------------------------------------------------------------------------
// CSR build v2, phase 1: block-local counting sort by bucket, append runs.
// ---------------------------------------------------------------------------
__global__ __launch_bounds__(256) void k_p1(const int* __restrict__ rows,
        const int* __restrict__ cols, const float* __restrict__ vals,
        int* __restrict__ bcnt, uint2* __restrict__ staging,
        uint4* __restrict__ ovf, int* __restrict__ ovf_cnt) {
    int t = blockIdx.y;
    int base = blockIdx.x * P1CHUNK;
    int tid = threadIdx.x;
    __shared__ int hist[256], sc[256], excl[256], cursor[256], gbase[256];
    __shared__ uint2 ebuf[P1CHUNK];
    __shared__ u16 ebuck[P1CHUNK];
    hist[tid] = 0;
    __syncthreads();
    const int*   rt = rows + (size_t)t * E_EDGES;
    const int*   ct = cols + (size_t)t * E_EDGES;
    const float* vt = vals + (size_t)t * E_EDGES;
    #pragma unroll
    for (int k = 0; k < P1CHUNK / 256; ++k) {
        int i = base + k * 256 + tid;
        if (i < E_EDGES) atomicAdd(&hist[rt[i] >> 7], 1);
    }
    __syncthreads();
    sc[tid] = hist[tid];
    __syncthreads();
    for (int off = 1; off < 256; off <<= 1) {
        int add = (tid >= off) ? sc[tid - off] : 0;
        __syncthreads();
        sc[tid] += add;
        __syncthreads();
    }
    excl[tid]   = sc[tid] - hist[tid];
    cursor[tid] = sc[tid] - hist[tid];
    __syncthreads();
    #pragma unroll
    for (int k = 0; k < P1CHUNK / 256; ++k) {
        int i = base + k * 256 + tid;
        if (i < E_EDGES) {
            int r = rt[i];
            int b = r >> 7;
            int s = atomicAdd(&cursor[b], 1);
            uint2 e;
            e.x = (unsigned)ct[i] | ((unsigned)(r & 127) << 15);
            e.y = __float_as_uint(vt[i]);
            ebuf[s]  = e;
            ebuck[s] = (u16)b;
        }
    }
    __syncthreads();
    if (hist[tid] > 0) gbase[tid] = atomicAdd(&bcnt[t * NBUCK + tid], hist[tid]);
    __syncthreads();
    int nvalid = min(P1CHUNK, E_EDGES - base);
    for (int s = tid; s < nvalid; s += 256) {
        int b = ebuck[s];
        int g = gbase[b] + (s - excl[b]);
        if (g < BCAP) {
            staging[((size_t)t * NBUCK + b) * BCAP + g] = ebuf[s];
        } else {
            int o = atomicAdd(ovf_cnt, 1);
            uint4 e4; e4.x = (unsigned)(t * NBUCK + b); e4.y = ebuf[s].x; e4.z = ebuf[s].y; e4.w = 0;
            ovf[o] = e4;
        }
    }
}

// phase 2a: exclusive scan of all bucket counts (2512 values), one block
__global__ void k_bscan(const int* __restrict__ bcnt, int* __restrict__ bbase,
                        int* __restrict__ row_ptr) {
    __shared__ int sh[256];
    __shared__ int carry;
    int tid = threadIdx.x;
    if (tid == 0) carry = 0;
    __syncthreads();
    for (int b0 = 0; b0 < T_SNAP * NBUCK; b0 += 256) {
        int i = b0 + tid;
        int v = (i < T_SNAP * NBUCK) ? bcnt[i] : 0;
        sh[tid] = v;
        __syncthreads();
        for (int off = 1; off < 256; off <<= 1) {
            int add = (tid >= off) ? sh[tid - off] : 0;
            __syncthreads();
            sh[tid] += add;
            __syncthreads();
        }
        if (i < T_SNAP * NBUCK) bbase[i] = carry + sh[tid] - v;
        __syncthreads();
        if (tid == 255) carry += sh[255];
        __syncthreads();
    }
    if (tid < T_SNAP) row_ptr[tid * (N_NODES + 1) + N_NODES] = E_EDGES;
}

// phase 2b: per-bucket row sort -> row_ptr + final colval
__global__ __launch_bounds__(256) void k_p2(const int* __restrict__ bcnt,
        const int* __restrict__ bbase, const uint2* __restrict__ staging,
        const uint4* __restrict__ ovf, const int* __restrict__ ovf_cnt,
        uint2* __restrict__ colval, int* __restrict__ row_ptr) {
    int b = blockIdx.x, t = blockIdx.y, tid = threadIdx.x;
    int idx = t * NBUCK + b;
    int cnt = bcnt[idx];
    int gb  = bbase[idx];
    __shared__ int hist[BROWS], cursor[BROWS], sc[BROWS];
    if (tid < BROWS) hist[tid] = 0;
    __syncthreads();
    int staged = min(cnt, BCAP);
    const uint2* st = staging + (size_t)idx * BCAP;
    for (int s = tid; s < staged; s += 256)
        atomicAdd(&hist[st[s].x >> 15], 1);
    int nov = (cnt > staged) ? *ovf_cnt : 0;
    for (int o = tid; o < nov; o += 256) {
        uint4 e = ovf[o];
        if ((int)e.x == idx) atomicAdd(&hist[(e.y >> 15) & 127], 1);
    }
    __syncthreads();
    if (tid < BROWS) sc[tid] = hist[tid];
    __syncthreads();
    for (int off = 1; off < BROWS; off <<= 1) {
        int add = (tid < BROWS && tid >= off) ? sc[tid - off] : 0;
        __syncthreads();
        if (tid < BROWS) sc[tid] += add;
        __syncthreads();
    }
    if (tid < BROWS) {
        int ex = sc[tid] - hist[tid];
        cursor[tid] = ex;
        int row = b * BROWS + tid;
        if (row < N_NODES)
            row_ptr[t * (N_NODES + 1) + row] = gb - t * E_EDGES + ex;
    }
    __syncthreads();
    for (int s = tid; s < staged; s += 256) {
        uint2 e = st[s];
        int rl = e.x >> 15;
        int pos = atomicAdd(&cursor[rl], 1);
        uint2 o2; o2.x = e.x & 0x7FFF; o2.y = e.y;
        colval[(size_t)gb + pos] = o2;
    }
    for (int o = tid; o < nov; o += 256) {
        uint4 e = ovf[o];
        if ((int)e.x == idx) {
            int rl = (e.y >> 15) & 127;
            int pos = atomicAdd(&cursor[rl], 1);
            uint2 o2; o2.x = e.y & 0x7FFF; o2.y = e.z;
            colval[(size_t)gb + pos] = o2;
        }
    }
}

// ---------------------------------------------------------------------------
// Conversions / weight builders
// ---------------------------------------------------------------------------
__global__ void k_cvt(const float* __restrict__ in, u16* __restrict__ out, int n4) {
    int i = blockIdx.x * 256 + threadIdx.x;
    if (i < n4) {
        float4 v = ((const float4*)in)[i];
        ushort4 o;
        o.x = f2b(v.x); o.y = f2b(v.y); o.z = f2b(v.z); o.w = f2b(v.w);
        ((ushort4*)out)[i] = o;
    }
}

__global__ void k_tcvt(const float* __restrict__ in, u16* __restrict__ out, int Kr, int Nc) {
    int i = blockIdx.x * 256 + threadIdx.x;
    if (i < Kr * Nc) {
        int k = i / Nc, n = i - k * Nc;
        out[(size_t)n * Kr + k] = f2b(in[i]);
    }
}

// 512-col interleave over concat(x,h)
__global__ void k_build_bg(const float* __restrict__ Wih, const float* __restrict__ Whh,
                           u16* __restrict__ Bg) {
    int i = blockIdx.x * 256 + threadIdx.x;
    if (i >= 512 * 256) return;
    int rr = i >> 8, k = i & 255;
    int c = rr >> 4, u = rr & 15, g = c & 3, jj = ((c >> 2) << 4) + u;
    float v;
    if (g == 0)      v = (k < 128) ? Wih[(size_t)jj * 128 + k]         : Whh[(size_t)jj * 128 + k - 128];
    else if (g == 1) v = (k < 128) ? Wih[(size_t)(128 + jj) * 128 + k] : Whh[(size_t)(128 + jj) * 128 + k - 128];
    else if (g == 2) v = (k < 128) ? Wih[(size_t)(256 + jj) * 128 + k] : 0.f;
    else             v = (k < 128) ? 0.f : Whh[(size_t)(256 + jj) * 128 + k - 128];
    Bg[i] = f2b(v);
}

__global__ void k_build_bgb(const float* __restrict__ bih, const float* __restrict__ bhh,
                            float* __restrict__ bgb) {
    int rr = blockIdx.x * 256 + threadIdx.x;
    if (rr >= 512) return;
    int c = rr >> 4, u = rr & 15, g = c & 3, jj = ((c >> 2) << 4) + u;
    float v;
    if (g == 0)      v = bih[jj] + bhh[jj];
    else if (g == 1) v = bih[128 + jj] + bhh[128 + jj];
    else if (g == 2) v = bih[256 + jj];
    else             v = bhh[256 + jj];
    bgb[rr] = v;
}

// ---------------------------------------------------------------------------
// SpMM layer0 (D=256): one row per wave, half-wave per edge stream, 2 streams
// (r7 version — at the random-gather memory-path roofline).
// ---------------------------------------------------------------------------
template<bool RELU>
__global__ __launch_bounds__(256) void k_spmm0(
        const int* __restrict__ rp_all, const uint2* __restrict__ cv_all,
        int t0, const u16* __restrict__ X,
        const float* __restrict__ bias, u16* __restrict__ Out) {
    int lane = threadIdx.x & 63;
    int row = blockIdx.x * 4 + (threadIdx.x >> 6);
    int tl = blockIdx.y, t = t0 + tl;
    const int*   rp = rp_all + (size_t)t * (N_NODES + 1);
    const uint2* cv = cv_all + (size_t)t * E_EDGES;
    int hw = lane >> 5, l = lane & 31;
    int s = rp[row], e = rp[row + 1];
    int k = s + hw;
    uint2 a0 = make_uint2(0u, 0u), a1 = make_uint2(0u, 0u);
    if (k < e)     a0 = cv[k];
    if (k + 2 < e) a1 = cv[k + 2];
#if HAVE_DOT2
    float acc[8] = {};
    for (; k < e; k += 4) {
        uint2 c0 = a0, c1 = a1;
        bool ok1 = (k + 2) < e;
        int e1 = e - 1;
        a0 = cv[min(k + 4, e1)];
        a1 = cv[min(k + 6, e1)];
        unsigned col1 = ok1 ? c1.x : c0.x;
        float va1f = ok1 ? __uint_as_float(c1.y) : 0.f;
        unsigned vv = (unsigned)f2b(__uint_as_float(c0.y)) | ((unsigned)f2b(va1f) << 16);
        uint4 x0 = *(const uint4*)(X + (size_t)c0.x * NHID + l * 8);
        uint4 x1 = *(const uint4*)(X + (size_t)col1 * NHID + l * 8);
        acc[0] = dot2b(pack_lo(x0.x, x1.x), vv, acc[0]);
        acc[1] = dot2b(pack_hi(x0.x, x1.x), vv, acc[1]);
        acc[2] = dot2b(pack_lo(x0.y, x1.y), vv, acc[2]);
        acc[3] = dot2b(pack_hi(x0.y, x1.y), vv, acc[3]);
        acc[4] = dot2b(pack_lo(x0.z, x1.z), vv, acc[4]);
        acc[5] = dot2b(pack_hi(x0.z, x1.z), vv, acc[5]);
        acc[6] = dot2b(pack_lo(x0.w, x1.w), vv, acc[6]);
        acc[7] = dot2b(pack_hi(x0.w, x1.w), vv, acc[7]);
    }
    #pragma unroll
    for (int i = 0; i < 8; ++i) {
        float v = acc[i];
        v += __shfl_xor(v, 32);
        v += bias[l * 8 + i];
        acc[i] = RELU ? fmaxf(v, 0.f) : v;
    }
    float* accw = acc;
#else
    float acc0[8] = {}, acc1[8] = {};
    for (; k < e; k += 4) {
        uint2 c0 = a0, c1 = a1;
        bool ok1 = (k + 2) < e;
        int e1 = e - 1;
        a0 = cv[min(k + 4, e1)];
        a1 = cv[min(k + 6, e1)];
        float va0 = __uint_as_float(c0.y);
        float va1 = ok1 ? __uint_as_float(c1.y) : 0.f;
        unsigned col1 = ok1 ? c1.x : c0.x;
        u16x8 x0 = *(const u16x8*)(X + (size_t)c0.x * NHID + l * 8);
        u16x8 x1 = *(const u16x8*)(X + (size_t)col1 * NHID + l * 8);
        #pragma unroll
        for (int i = 0; i < 8; ++i) {
            acc0[i] = fmaf(va0, b2f(x0[i]), acc0[i]);
            acc1[i] = fmaf(va1, b2f(x1[i]), acc1[i]);
        }
    }
    #pragma unroll
    for (int i = 0; i < 8; ++i) {
        float v = acc0[i] + acc1[i];
        v += __shfl_xor(v, 32);
        v += bias[l * 8 + i];
        acc0[i] = RELU ? fmaxf(v, 0.f) : v;
    }
    float* accw = acc0;
#endif
    if (hw == 0) {
        u16x8 o;
        #pragma unroll
        for (int i = 0; i < 8; ++i) o[i] = f2b(accw[i]);
        *(u16x8*)(Out + ((size_t)tl * N_NODES + row) * NHID + l * 8) = o;
    }
}

// ---------------------------------------------------------------------------
// SpMM layer1 (D=128): quarter-wave per edge stream, 2 streams (r7 version).
// ---------------------------------------------------------------------------
template<bool RELU>
__global__ __launch_bounds__(256) void k_spmm1(
        const int* __restrict__ rp_all, const uint2* __restrict__ cv_all,
        int t0, const u16* __restrict__ X, size_t xtstride,
        const float* __restrict__ bias, u16* __restrict__ Out) {
    int lane = threadIdx.x & 63;
    int row = blockIdx.x * 4 + (threadIdx.x >> 6);
    int tl = blockIdx.y, t = t0 + tl;
    const int*   rp = rp_all + (size_t)t * (N_NODES + 1);
    const uint2* cv = cv_all + (size_t)t * E_EDGES;
    const u16*   Xt = X + xtstride * tl;
    int qw = lane >> 4, l = lane & 15;
    int s = rp[row], e = rp[row + 1];
    int k = s + qw;
    uint2 a0 = make_uint2(0u, 0u), a1 = make_uint2(0u, 0u);
    if (k < e)     a0 = cv[k];
    if (k + 4 < e) a1 = cv[k + 4];
#if HAVE_DOT2
    float acc[8] = {};
    for (; k < e; k += 8) {
        uint2 c0 = a0, c1 = a1;
        bool ok1 = (k + 4) < e;
        int e1 = e - 1;
        a0 = cv[min(k + 8, e1)];
        a1 = cv[min(k + 12, e1)];
        unsigned col1 = ok1 ? c1.x : c0.x;
        float va1f = ok1 ? __uint_as_float(c1.y) : 0.f;
        unsigned vv = (unsigned)f2b(__uint_as_float(c0.y)) | ((unsigned)f2b(va1f) << 16);
        uint4 x0 = *(const uint4*)(Xt + (size_t)c0.x * NOUT + l * 8);
        uint4 x1 = *(const uint4*)(Xt + (size_t)col1 * NOUT + l * 8);
        acc[0] = dot2b(pack_lo(x0.x, x1.x), vv, acc[0]);
        acc[1] = dot2b(pack_hi(x0.x, x1.x), vv, acc[1]);
        acc[2] = dot2b(pack_lo(x0.y, x1.y), vv, acc[2]);
        acc[3] = dot2b(pack_hi(x0.y, x1.y), vv, acc[3]);
        acc[4] = dot2b(pack_lo(x0.z, x1.z), vv, acc[4]);
        acc[5] = dot2b(pack_hi(x0.z, x1.z), vv, acc[5]);
        acc[6] = dot2b(pack_lo(x0.w, x1.w), vv, acc[6]);
        acc[7] = dot2b(pack_hi(x0.w, x1.w), vv, acc[7]);
    }
    #pragma unroll
    for (int i = 0; i < 8; ++i) {
        float v = acc[i];
        v += __shfl_xor(v, 32);
        v += __shfl_xor(v, 16);
        v += bias[l * 8 + i];
        acc[i] = RELU ? fmaxf(v, 0.f) : v;
    }
    float* accw = acc;
#else
    float acc0[8] = {}, acc1[8] = {};
    for (; k < e; k += 8) {
        uint2 c0 = a0, c1 = a1;
        bool ok1 = (k + 4) < e;
        int e1 = e - 1;
        a0 = cv[min(k + 8, e1)];
        a1 = cv[min(k + 12, e1)];
        float va0 = __uint_as_float(c0.y);
        float va1 = ok1 ? __uint_as_float(c1.y) : 0.f;
        unsigned col1 = ok1 ? c1.x : c0.x;
        u16x8 x0 = *(const u16x8*)(Xt + (size_t)c0.x * NOUT + l * 8);
        u16x8 x1 = *(const u16x8*)(Xt + (size_t)col1 * NOUT + l * 8);
        #pragma unroll
        for (int i = 0; i < 8; ++i) {
            acc0[i] = fmaf(va0, b2f(x0[i]), acc0[i]);
            acc1[i] = fmaf(va1, b2f(x1[i]), acc1[i]);
        }
    }
    #pragma unroll
    for (int i = 0; i < 8; ++i) {
        float v = acc0[i] + acc1[i];
        v += __shfl_xor(v, 32);
        v += __shfl_xor(v, 16);
        v += bias[l * 8 + i];
        acc0[i] = RELU ? fmaxf(v, 0.f) : v;
    }
    float* accw = acc0;
#endif
    if (qw == 0) {
        u16x8 o;
        #pragma unroll
        for (int i = 0; i < 8; ++i) o[i] = f2b(accw[i]);
        *(u16x8*)(Out + ((size_t)tl * N_NODES + row) * NOUT + l * 8) = o;
    }
}

// ---------------------------------------------------------------------------
// bf16 MFMA GEMM: C[M,Nc] = A[M,K] @ B^T (+bias), out bf16. tile 64x128.
// ---------------------------------------------------------------------------
template<int KC, bool BIAS>
__global__ __launch_bounds__(256) void k_mgemm(
        const u16* __restrict__ A, const u16* __restrict__ B, int ldb,
        const float* __restrict__ bias, u16* __restrict__ C, int ldc, int M) {
    constexpr int K = KC * 32;
    __shared__ bf16x8 frag[8 * KC * 64];
    int tid = threadIdx.x, lane = tid & 63, wave = tid >> 6;
    int m0 = blockIdx.y * 64, n0 = blockIdx.x * 128;

    for (int f = wave; f < 8 * KC; f += 4) {
        int nl = f / KC, kc = f % KC;
        frag[f * 64 + lane] = *(const bf16x8*)(B + (size_t)(n0 + nl * 16 + (lane & 15)) * ldb
                                               + kc * 32 + ((lane >> 4) << 3));
    }
    __syncthreads();

    int arow = m0 + wave * 16 + (lane & 15);
    bool rowok = arow < M;
    const u16* ap = A + (size_t)arow * K + ((lane >> 4) << 3);
    bf16x8 zf = {0, 0, 0, 0, 0, 0, 0, 0};
    bf16x8 af[KC];
    #pragma unroll
    for (int kc = 0; kc < KC; ++kc)
        af[kc] = rowok ? *(const bf16x8*)(ap + kc * 32) : zf;

    f32x4 acc[8] = {};
    #pragma unroll
    for (int kc = 0; kc < KC; ++kc)
        #pragma unroll
        for (int nl = 0; nl < 8; ++nl)
            acc[nl] = __builtin_amdgcn_mfma_f32_16x16x32_bf16(
                af[kc], frag[(nl * KC + kc) * 64 + lane], acc[nl], 0, 0, 0);

    int r0 = m0 + wave * 16 + ((lane >> 4) << 2);
    #pragma unroll
    for (int nl = 0; nl < 8; ++nl) {
        int col = n0 + nl * 16 + (lane & 15);
        float bv = BIAS ? bias[col] : 0.f;
        #pragma unroll
        for (int r = 0; r < 4; ++r) {
            int row = r0 + r;
            if (row < M) C[(size_t)row * ldc + col] = f2b(acc[nl][r] + bv);
        }
    }
}

// ---------------------------------------------------------------------------
// Fused all-16-step GRU: wave-specialized, Bg resident in VGPRs.
// Block = 16 nodes, 512 thr / 8 waves, 1250 blocks (N = 1250*16 exactly ->
// no bounds checks), launch_bounds(512,2) (proven: no spill). Cross-barrier
// X2 prefetch: step t+1's x-fragments are loaded while step t's epilogue +
// barrier drain, hiding the only global latency in the loop. Wave w:
// quadrant q=w>>1, half hb=w&1; its 4 nl-tiles are the gates (r,z,i,n) of
// hidden slice jj=(2q+hb)*16+u. h bf16 double-buffered in padded LDS;
// h fp32 in regs. Fast hw sigmoid/tanh. One barrier per step.
// ---------------------------------------------------------------------------
__global__ __launch_bounds__(512, 2) void k_gru_fused2(
        const u16* __restrict__ X2_all, const u16* __restrict__ Bg,
        const float* __restrict__ bgb, float* __restrict__ H) {
    __shared__ u16 hbuf[2][16][132];           // 2 x 4.2 KB, +4 pad
    int tid = threadIdx.x, lane = tid & 63, wave = tid >> 6;
    int q = wave >> 1, hb = wave & 1;
    int u = lane & 15, kgrp = lane >> 4;       // kgrp 0..3
    int m0 = blockIdx.x * 16;
    int jj = (2 * q + hb) * 16 + u;            // this wave's hidden slice col

    // ---- load this wave's 32 B-fragments into registers (once) ----
    bf16x8 bfrag[4][8];
    #pragma unroll
    for (int g = 0; g < 4; ++g)
        #pragma unroll
        for (int kc = 0; kc < 8; ++kc)
            bfrag[g][kc] = *(const bf16x8*)(Bg
                + (size_t)(q * 128 + (4 * hb + g) * 16 + u) * 256
                + kc * 32 + kgrp * 8);

    float bR = bgb[q * 128 + (4 * hb + 0) * 16 + u];
    float bZ = bgb[q * 128 + (4 * hb + 1) * 16 + u];
    float bI = bgb[q * 128 + (4 * hb + 2) * 16 + u];
    float bH = bgb[q * 128 + (4 * hb + 3) * 16 + u];

    for (int i = tid; i < 16 * 132; i += 512) ((u16*)hbuf[0])[i] = 0;

    float hstate[4] = {};                      // [r] fp32 state
    int arow = m0 + u;
    const u16* aptr = X2_all + (size_t)arow * 128 + kgrp * 8;

    // prologue: preload step-0 x-fragments
    bf16x8 afx[4];
    #pragma unroll
    for (int kc = 0; kc < 4; ++kc)
        afx[kc] = *(const bf16x8*)(aptr + kc * 32);
    __syncthreads();

    for (int t = 0; t < T_SNAP; ++t) {
        int rb = t & 1, wb = rb ^ 1;
        bf16x8 afh[4];
        #pragma unroll
        for (int kc = 0; kc < 4; ++kc)
            afh[kc] = *(const bf16x8*)&hbuf[rb][u][kc * 32 + kgrp * 8];

        f32x4 acc[4] = {};
        #pragma unroll
        for (int kc = 0; kc < 4; ++kc)
            #pragma unroll
            for (int g = 0; g < 4; ++g)
                acc[g] = __builtin_amdgcn_mfma_f32_16x16x32_bf16(
                    afx[kc], bfrag[g][kc], acc[g], 0, 0, 0);
        #pragma unroll
        for (int kc = 0; kc < 4; ++kc)
            #pragma unroll
            for (int g = 0; g < 4; ++g)
                acc[g] = __builtin_amdgcn_mfma_f32_16x16x32_bf16(
                    afh[kc], bfrag[g][4 + kc], acc[g], 0, 0, 0);

        // prefetch next step's x-fragments (independent of h; hides HBM/L2
        // latency under the epilogue + barrier + next step's LDS reads)
        bf16x8 afn[4];
        if (t + 1 < T_SNAP) {
            const u16* ap2 = aptr + (size_t)(t + 1) * N_NODES * 128;
            #pragma unroll
            for (int kc = 0; kc < 4; ++kc)
                afn[kc] = *(const bf16x8*)(ap2 + kc * 32);
        } else {
            #pragma unroll
            for (int kc = 0; kc < 4; ++kc) afn[kc] = afx[kc];
        }

        #pragma unroll
        for (int r = 0; r < 4; ++r) {
            int lrow = kgrp * 4 + r;
            float rg = fsig(acc[0][r] + bR);
            float zg = fsig(acc[1][r] + bZ);
            float ng = ftanh(acc[2][r] + bI + rg * (acc[3][r] + bH));
            float hn = (1.f - zg) * ng + zg * hstate[r];
            hstate[r] = hn;
            hbuf[wb][lrow][jj] = f2b(hn);
        }
        __syncthreads();   // wb complete before next step reads it
        #pragma unroll
        for (int kc = 0; kc < 4; ++kc) afx[kc] = afn[kc];
    }
    #pragma unroll
    for (int r = 0; r < 4; ++r) {
        int row = m0 + kgrp * 4 + r;
        H[(size_t)row * HDIM + jj] = hstate[r];
    }
}

// ---------------------------------------------------------------------------
// BatchNorm
// ---------------------------------------------------------------------------
__global__ void k_bnstats(const float* __restrict__ h, float* __restrict__ stats) {
    int j = threadIdx.x;
    int r0 = blockIdx.x * 200;
    float s = 0.f, sq = 0.f;
    for (int r = r0; r < r0 + 200; ++r) {
        float v = h[(size_t)r * HDIM + j];
        s += v; sq += v * v;
    }
    atomicAdd(&stats[j], s);
    atomicAdd(&stats[128 + j], sq);
}

__global__ void k_bnapply(const float* __restrict__ h, const float* __restrict__ stats,
                          const float* __restrict__ gamma, const float* __restrict__ beta,
                          u16* __restrict__ emb) {
    int i = blockIdx.x * 256 + threadIdx.x;
    if (i >= N_NODES * HDIM) return;
    int j = i & 127;
    float mean = stats[j] * (1.f / N_NODES);
    float var  = stats[128 + j] * (1.f / N_NODES) - mean * mean;
    emb[i] = f2b((h[i] - mean) * rsqrtf(var + BN_EPS) * gamma[j] + beta[j]);
}

// ---------------------------------------------------------------------------
// Edge predictor
// ---------------------------------------------------------------------------
__global__ __launch_bounds__(256) void k_edge(const int* __restrict__ edges,
        const u16* __restrict__ P, const u16* __restrict__ Q,
        const float* __restrict__ We2, const float* __restrict__ be2,
        float* __restrict__ out) {
    int e = blockIdx.x * 4 + (threadIdx.x >> 6);
    int lane = threadIdx.x & 63;
    if (e >= EP_EDGES) return;
    int u = edges[e];
    int v = edges[EP_EDGES + e];
    ushort4 pv = *(const ushort4*)(P + (size_t)u * NHID_E + lane * 4);
    ushort4 qv = *(const ushort4*)(Q + (size_t)v * NHID_E + lane * 4);
    const float4* w = (const float4*)(We2 + lane * 8);
    float4 w0 = w[0], w1 = w[1];
    float h0 = fmaxf(b2f(pv.x) + b2f(qv.x), 0.f);
    float h1 = fmaxf(b2f(pv.y) + b2f(qv.y), 0.f);
    float h2 = fmaxf(b2f(pv.z) + b2f(qv.z), 0.f);
    float h3 = fmaxf(b2f(pv.w) + b2f(qv.w), 0.f);
    float l0 = h0 * w0.x + h1 * w0.z + h2 * w1.x + h3 * w1.z;
    float l1 = h0 * w0.y + h1 * w0.w + h2 * w1.y + h3 * w1.w;
    #pragma unroll
    for (int off = 32; off > 0; off >>= 1) {
        l0 += __shfl_down(l0, off);
        l1 += __shfl_down(l1, off);
    }
    if (lane == 0) {
        l0 += be2[0]; l1 += be2[1];
        float m = fmaxf(l0, l1);
        float lse = m + logf(expf(l0 - m) + expf(l1 - m));
        out[(size_t)e * 2 + 0] = l0 - lse;
        out[(size_t)e * 2 + 1] = l1 - lse;
    }
}

// ---------------------------------------------------------------------------
extern "C" void kernel_launch(void* const* d_in, const int* in_sizes, int n_in,
                              void* d_out, int out_size, void* d_ws, size_t ws_size,
                              hipStream_t stream) {
    const int*   adj_rows = (const int*)  d_in[0];
    const int*   adj_cols = (const int*)  d_in[1];
    const float* adj_vals = (const float*)d_in[2];
    const int*   edges    = (const int*)  d_in[3];
    const float* W0   = (const float*)d_in[4];
    const float* b0   = (const float*)d_in[5];
    const float* W1   = (const float*)d_in[6];
    const float* b1   = (const float*)d_in[7];
    const float* W_ih = (const float*)d_in[8];
    const float* W_hh = (const float*)d_in[9];
    const float* b_ih = (const float*)d_in[10];
    const float* b_hh = (const float*)d_in[11];
    const float* gamma = (const float*)d_in[12];
    const float* beta  = (const float*)d_in[13];
    const float* We1  = (const float*)d_in[14];
    const float* be1  = (const float*)d_in[15];
    const float* We2  = (const float*)d_in[16];
    const float* be2  = (const float*)d_in[17];
    float* out = (float*)d_out;

    char* ws = (char*)d_ws;
    size_t off = 0;
    auto alloc = [&](size_t bytes) -> void* {
        void* p = ws + off;
        off += (bytes + 255) & ~(size_t)255;
        return p;
    };
    // ---- persistent ----
    int*   row_ptr = (int*)  alloc((size_t)T_SNAP * (N_NODES + 1) * 4);
    uint2* colval  = (uint2*)alloc((size_t)T_SNAP * E_EDGES * 8);
    u16*   W0_bf   = (u16*)  alloc((size_t)N_NODES * NHID * 2);
    u16*   W1t     = (u16*)  alloc((size_t)NOUT * NHID * 2);
    u16*   We1T    = (u16*)  alloc((size_t)NHID_E * 256 * 2);
    u16*   BgB     = (u16*)  alloc((size_t)512 * 256 * 2);
    float* bgbB    = (float*)alloc(512 * 4);
    float* h       = (float*)alloc((size_t)N_NODES * HDIM * 4);
    float* stats   = (float*)alloc(256 * 4);
    int*   bcnt    = (int*)  alloc((size_t)T_SNAP * NBUCK * 4);
    int*   bbase   = (int*)  alloc((size_t)T_SNAP * NBUCK * 4);
    int*   ovf_cnt = (int*)  alloc(256);
    size_t mark = off;

    // ---- union region: CSR phase ----
    off = mark;
    uint2* staging = (uint2*)alloc((size_t)T_SNAP * NBUCK * BCAP * 8);
    uint4* ovf     = (uint4*)alloc((size_t)T_SNAP * E_EDGES * 16);
    size_t csr_end = off;

    // ---- union region: compute phase (BT adaptive 8 -> 4) ----
    int BT = 8;
    u16 *X0_b, *Y_b, *X2_all;
    size_t comp_end;
    for (;;) {
        off = mark;
        X0_b   = (u16*)alloc((size_t)BT * N_NODES * NHID * 2);
        Y_b    = (u16*)alloc((size_t)BT * N_NODES * NOUT * 2);
        X2_all = (u16*)alloc((size_t)T_SNAP * N_NODES * NOUT * 2);
        comp_end = off;
        if (comp_end <= ws_size || BT == 4) break;
        BT >>= 1;
    }

    // ---- union region: post phase ----
    off = mark;
    u16* emb = (u16*)alloc((size_t)N_NODES * HDIM * 2);
    u16* P   = (u16*)alloc((size_t)N_NODES * NHID_E * 2);
    u16* Q   = (u16*)alloc((size_t)N_NODES * NHID_E * 2);
    size_t post_end = off;

    size_t need = csr_end;
    if (comp_end > need) need = comp_end;
    if (post_end > need) need = post_end;
    if (need > ws_size) return;   // visible failure instead of corruption

    hipMemsetAsync(bcnt,    0, (size_t)T_SNAP * NBUCK * 4, stream);
    hipMemsetAsync(ovf_cnt, 0, 256, stream);
    hipMemsetAsync(stats,   0, 256 * 4, stream);

    // ---- CSR build v2 ----
    dim3 p1g((E_EDGES + P1CHUNK - 1) / P1CHUNK, T_SNAP);
    k_p1   <<<p1g, 256, 0, stream>>>(adj_rows, adj_cols, adj_vals, bcnt, staging, ovf, ovf_cnt);
    k_bscan<<<1, 256, 0, stream>>>(bcnt, bbase, row_ptr);
    k_p2   <<<dim3(NBUCK, T_SNAP), 256, 0, stream>>>(bcnt, bbase, staging, ovf, ovf_cnt,
                                                     colval, row_ptr);

    // ---- weight conversions ----
    k_cvt      <<<(N_NODES * NHID / 4 + 255) / 256, 256, 0, stream>>>(W0, W0_bf, N_NODES * NHID / 4);
    k_tcvt     <<<(NHID * NOUT + 255) / 256,  256, 0, stream>>>(W1, W1t, NHID, NOUT);
    k_tcvt     <<<(256 * NHID_E + 255) / 256, 256, 0, stream>>>(We1, We1T, 256, NHID_E);
    k_build_bg <<<(512 * 256 + 255) / 256, 256, 0, stream>>>(W_ih, W_hh, BgB);
    k_build_bgb<<<2, 256, 0, stream>>>(b_ih, b_hh, bgbB);

    // ---- batched GCN: layer0 spmm -> X0@W1 -> layer1 spmm -> X2_all ----
    for (int g = 0; g < T_SNAP; g += BT) {
        k_spmm0<true><<<dim3(N_NODES / 4, BT), 256, 0, stream>>>(
            row_ptr, colval, g, W0_bf, b0, X0_b);
        int M = BT * N_NODES;
        k_mgemm<8, false><<<dim3(1, (M + 63) / 64), 256, 0, stream>>>(
            X0_b, W1t, NHID, nullptr, Y_b, NOUT, M);
        k_spmm1<false><<<dim3(N_NODES / 4, BT), 256, 0, stream>>>(
            row_ptr, colval, g, Y_b, (size_t)N_NODES * NOUT, b1,
            X2_all + (size_t)g * N_NODES * NOUT);
    }

    // ---- GRU: all 16 steps fused, Bg in VGPRs, 1250 blocks (16 nodes each),
    //      cross-barrier X2 prefetch ----
    k_gru_fused2<<<N_NODES / 16, 512, 0, stream>>>(X2_all, BgB, bgbB, h);

    // ---- BatchNorm ----
    k_bnstats<<<100, 128, 0, stream>>>(h, stats);
    k_bnapply<<<(N_NODES * HDIM + 255) / 256, 256, 0, stream>>>(h, stats, gamma, beta, emb);

    // ---- Edge MLP precompute + predictor ----
    k_mgemm<4, true><<<dim3(2, (N_NODES + 63) / 64), 256, 0, stream>>>(
        emb, We1T, 256, be1, P, NHID_E, N_NODES);
    k_mgemm<4, false><<<dim3(2, (N_NODES + 63) / 64), 256, 0, stream>>>(
        emb, We1T + 128, 256, nullptr, Q, NHID_E, N_NODES);
    k_edge<<<(EP_EDGES + 3) / 4, 256, 0, stream>>>(edges, P, Q, We2, be2, out);
}

// Round 17
// 816.186 us; speedup vs baseline: 1.3840x; 1.0006x over previous
//
#include <hip/hip_runtime.h>
#include <math.h>

#define N_NODES 20000
#define NHID    256
#define NOUT    128
#define HDIM    128
#define NHID_E  256
#define T_SNAP  16
#define E_EDGES 320000
#define EP_EDGES 100000
#define BN_EPS  1e-5f

#define BROWS 128                    // rows per bucket
#define NBUCK 157                    // ceil(N_NODES / BROWS)
#define BCAP  4096                   // staging capacity per bucket
#define P1CHUNK 2048                 // edges per k_p1 block (25KB LDS -> 6 blk/CU)

typedef unsigned short u16;
typedef __attribute__((ext_vector_type(8))) short bf16x8;
typedef __attribute__((ext_vector_type(8))) unsigned short u16x8;
typedef __attribute__((ext_vector_type(4))) float f32x4;

__device__ __forceinline__ u16 f2b(float f) {
    unsigned u = __float_as_uint(f);
    u += 0x7FFFu + ((u >> 16) & 1u);
    return (u16)(u >> 16);
}
__device__ __forceinline__ float b2f(u16 s) { return __uint_as_float(((unsigned)s) << 16); }

// ---- fast transcendentals (v_exp_f32 / v_rcp_f32), guarded ----
__device__ __forceinline__ float fexp2(float x) {
#if __has_builtin(__builtin_amdgcn_exp2f)
    return __builtin_amdgcn_exp2f(x);
#else
    return exp2f(x);
#endif
}
__device__ __forceinline__ float frcp(float x) {
#if __has_builtin(__builtin_amdgcn_rcpf)
    return __builtin_amdgcn_rcpf(x);
#else
    return 1.f / x;
#endif
}
__device__ __forceinline__ float fsig(float x) {
    return frcp(1.f + fexp2(x * -1.4426950408889634f));
}
__device__ __forceinline__ float ftanh(float x) {
    float t = fexp2(x * 2.8853900817779268f);
    return 1.f - 2.f * frcp(t + 1.f);
}

// ---- bf16 dot2 path (guarded; falls back to shl+fma if builtin absent) ----
#if __has_builtin(__builtin_amdgcn_fdot2_f32_bf16)
#define HAVE_DOT2 1
typedef __attribute__((ext_vector_type(2))) __bf16 bf2v;
__device__ __forceinline__ float dot2b(unsigned x, unsigned v, float acc) {
    return __builtin_amdgcn_fdot2_f32_bf16(
        __builtin_bit_cast(bf2v, x), __builtin_bit_cast(bf2v, v), acc, false);
}
__device__ __forceinline__ unsigned pack_lo(unsigned a, unsigned b) {
#if __has_builtin(__builtin_amdgcn_perm)
    return __builtin_amdgcn_perm(a, b, 0x01000504u);   // (a.e0 | b.e0<<16)
#else
    return (a & 0xFFFFu) | (b << 16);
#endif
}
__device__ __forceinline__ unsigned pack_hi(unsigned a, unsigned b) {
#if __has_builtin(__builtin_amdgcn_perm)
    return __builtin_amdgcn_perm(a, b, 0x03020706u);   // (a.e1 | b.e1<<16)
#else
    return (a >> 16) | (b & 0xFFFF0000u);
#endif
}
#else
#define HAVE_DOT2 0
#endif

// ---------------------------------------------------------------------------
// CSR build v2, phase 1: block-local counting sort by bucket, append runs.
// ---------------------------------------------------------------------------
__global__ __launch_bounds__(256) void k_p1(const int* __restrict__ rows,
        const int* __restrict__ cols, const float* __restrict__ vals,
        int* __restrict__ bcnt, uint2* __restrict__ staging,
        uint4* __restrict__ ovf, int* __restrict__ ovf_cnt) {
    int t = blockIdx.y;
    int base = blockIdx.x * P1CHUNK;
    int tid = threadIdx.x;
    __shared__ int hist[256], sc[256], excl[256], cursor[256], gbase[256];
    __shared__ uint2 ebuf[P1CHUNK];
    __shared__ u16 ebuck[P1CHUNK];
    hist[tid] = 0;
    __syncthreads();
    const int*   rt = rows + (size_t)t * E_EDGES;
    const int*   ct = cols + (size_t)t * E_EDGES;
    const float* vt = vals + (size_t)t * E_EDGES;
    #pragma unroll
    for (int k = 0; k < P1CHUNK / 256; ++k) {
        int i = base + k * 256 + tid;
        if (i < E_EDGES) atomicAdd(&hist[rt[i] >> 7], 1);
    }
    __syncthreads();
    sc[tid] = hist[tid];
    __syncthreads();
    for (int off = 1; off < 256; off <<= 1) {
        int add = (tid >= off) ? sc[tid - off] : 0;
        __syncthreads();
        sc[tid] += add;
        __syncthreads();
    }
    excl[tid]   = sc[tid] - hist[tid];
    cursor[tid] = sc[tid] - hist[tid];
    __syncthreads();
    #pragma unroll
    for (int k = 0; k < P1CHUNK / 256; ++k) {
        int i = base + k * 256 + tid;
        if (i < E_EDGES) {
            int r = rt[i];
            int b = r >> 7;
            int s = atomicAdd(&cursor[b], 1);
            uint2 e;
            e.x = (unsigned)ct[i] | ((unsigned)(r & 127) << 15);
            e.y = __float_as_uint(vt[i]);
            ebuf[s]  = e;
            ebuck[s] = (u16)b;
        }
    }
    __syncthreads();
    if (hist[tid] > 0) gbase[tid] = atomicAdd(&bcnt[t * NBUCK + tid], hist[tid]);
    __syncthreads();
    int nvalid = min(P1CHUNK, E_EDGES - base);
    for (int s = tid; s < nvalid; s += 256) {
        int b = ebuck[s];
        int g = gbase[b] + (s - excl[b]);
        if (g < BCAP) {
            staging[((size_t)t * NBUCK + b) * BCAP + g] = ebuf[s];
        } else {
            int o = atomicAdd(ovf_cnt, 1);
            uint4 e4; e4.x = (unsigned)(t * NBUCK + b); e4.y = ebuf[s].x; e4.z = ebuf[s].y; e4.w = 0;
            ovf[o] = e4;
        }
    }
}

// phase 2a: exclusive scan of all bucket counts (2512 values), one block
__global__ void k_bscan(const int* __restrict__ bcnt, int* __restrict__ bbase,
                        int* __restrict__ row_ptr) {
    __shared__ int sh[256];
    __shared__ int carry;
    int tid = threadIdx.x;
    if (tid == 0) carry = 0;
    __syncthreads();
    for (int b0 = 0; b0 < T_SNAP * NBUCK; b0 += 256) {
        int i = b0 + tid;
        int v = (i < T_SNAP * NBUCK) ? bcnt[i] : 0;
        sh[tid] = v;
        __syncthreads();
        for (int off = 1; off < 256; off <<= 1) {
            int add = (tid >= off) ? sh[tid - off] : 0;
            __syncthreads();
            sh[tid] += add;
            __syncthreads();
        }
        if (i < T_SNAP * NBUCK) bbase[i] = carry + sh[tid] - v;
        __syncthreads();
        if (tid == 255) carry += sh[255];
        __syncthreads();
    }
    if (tid < T_SNAP) row_ptr[tid * (N_NODES + 1) + N_NODES] = E_EDGES;
}

// phase 2b: per-bucket row sort -> row_ptr + final colval
__global__ __launch_bounds__(256) void k_p2(const int* __restrict__ bcnt,
        const int* __restrict__ bbase, const uint2* __restrict__ staging,
        const uint4* __restrict__ ovf, const int* __restrict__ ovf_cnt,
        uint2* __restrict__ colval, int* __restrict__ row_ptr) {
    int b = blockIdx.x, t = blockIdx.y, tid = threadIdx.x;
    int idx = t * NBUCK + b;
    int cnt = bcnt[idx];
    int gb  = bbase[idx];
    __shared__ int hist[BROWS], cursor[BROWS], sc[BROWS];
    if (tid < BROWS) hist[tid] = 0;
    __syncthreads();
    int staged = min(cnt, BCAP);
    const uint2* st = staging + (size_t)idx * BCAP;
    for (int s = tid; s < staged; s += 256)
        atomicAdd(&hist[st[s].x >> 15], 1);
    int nov = (cnt > staged) ? *ovf_cnt : 0;
    for (int o = tid; o < nov; o += 256) {
        uint4 e = ovf[o];
        if ((int)e.x == idx) atomicAdd(&hist[(e.y >> 15) & 127], 1);
    }
    __syncthreads();
    if (tid < BROWS) sc[tid] = hist[tid];
    __syncthreads();
    for (int off = 1; off < BROWS; off <<= 1) {
        int add = (tid < BROWS && tid >= off) ? sc[tid - off] : 0;
        __syncthreads();
        if (tid < BROWS) sc[tid] += add;
        __syncthreads();
    }
    if (tid < BROWS) {
        int ex = sc[tid] - hist[tid];
        cursor[tid] = ex;
        int row = b * BROWS + tid;
        if (row < N_NODES)
            row_ptr[t * (N_NODES + 1) + row] = gb - t * E_EDGES + ex;
    }
    __syncthreads();
    for (int s = tid; s < staged; s += 256) {
        uint2 e = st[s];
        int rl = e.x >> 15;
        int pos = atomicAdd(&cursor[rl], 1);
        uint2 o2; o2.x = e.x & 0x7FFF; o2.y = e.y;
        colval[(size_t)gb + pos] = o2;
    }
    for (int o = tid; o < nov; o += 256) {
        uint4 e = ovf[o];
        if ((int)e.x == idx) {
            int rl = (e.y >> 15) & 127;
            int pos = atomicAdd(&cursor[rl], 1);
            uint2 o2; o2.x = e.y & 0x7FFF; o2.y = e.z;
            colval[(size_t)gb + pos] = o2;
        }
    }
}

// ---------------------------------------------------------------------------
// Conversions / weight builders
// ---------------------------------------------------------------------------
__global__ void k_cvt(const float* __restrict__ in, u16* __restrict__ out, int n4) {
    int i = blockIdx.x * 256 + threadIdx.x;
    if (i < n4) {
        float4 v = ((const float4*)in)[i];
        ushort4 o;
        o.x = f2b(v.x); o.y = f2b(v.y); o.z = f2b(v.z); o.w = f2b(v.w);
        ((ushort4*)out)[i] = o;
    }
}

__global__ void k_tcvt(const float* __restrict__ in, u16* __restrict__ out, int Kr, int Nc) {
    int i = blockIdx.x * 256 + threadIdx.x;
    if (i < Kr * Nc) {
        int k = i / Nc, n = i - k * Nc;
        out[(size_t)n * Kr + k] = f2b(in[i]);
    }
}

// 512-col interleave over concat(x,h)
__global__ void k_build_bg(const float* __restrict__ Wih, const float* __restrict__ Whh,
                           u16* __restrict__ Bg) {
    int i = blockIdx.x * 256 + threadIdx.x;
    if (i >= 512 * 256) return;
    int rr = i >> 8, k = i & 255;
    int c = rr >> 4, u = rr & 15, g = c & 3, jj = ((c >> 2) << 4) + u;
    float v;
    if (g == 0)      v = (k < 128) ? Wih[(size_t)jj * 128 + k]         : Whh[(size_t)jj * 128 + k - 128];
    else if (g == 1) v = (k < 128) ? Wih[(size_t)(128 + jj) * 128 + k] : Whh[(size_t)(128 + jj) * 128 + k - 128];
    else if (g == 2) v = (k < 128) ? Wih[(size_t)(256 + jj) * 128 + k] : 0.f;
    else             v = (k < 128) ? 0.f : Whh[(size_t)(256 + jj) * 128 + k - 128];
    Bg[i] = f2b(v);
}

__global__ void k_build_bgb(const float* __restrict__ bih, const float* __restrict__ bhh,
                            float* __restrict__ bgb) {
    int rr = blockIdx.x * 256 + threadIdx.x;
    if (rr >= 512) return;
    int c = rr >> 4, u = rr & 15, g = c & 3, jj = ((c >> 2) << 4) + u;
    float v;
    if (g == 0)      v = bih[jj] + bhh[jj];
    else if (g == 1) v = bih[128 + jj] + bhh[128 + jj];
    else if (g == 2) v = bih[256 + jj];
    else             v = bhh[256 + jj];
    bgb[rr] = v;
}

// ---------------------------------------------------------------------------
// SpMM layer0 (D=256): one row per wave, half-wave per edge stream, 2 streams
// (r7 version — at the random-gather memory-path roofline).
// ---------------------------------------------------------------------------
template<bool RELU>
__global__ __launch_bounds__(256) void k_spmm0(
        const int* __restrict__ rp_all, const uint2* __restrict__ cv_all,
        int t0, const u16* __restrict__ X,
        const float* __restrict__ bias, u16* __restrict__ Out) {
    int lane = threadIdx.x & 63;
    int row = blockIdx.x * 4 + (threadIdx.x >> 6);
    int tl = blockIdx.y, t = t0 + tl;
    const int*   rp = rp_all + (size_t)t * (N_NODES + 1);
    const uint2* cv = cv_all + (size_t)t * E_EDGES;
    int hw = lane >> 5, l = lane & 31;
    int s = rp[row], e = rp[row + 1];
    int k = s + hw;
    uint2 a0 = make_uint2(0u, 0u), a1 = make_uint2(0u, 0u);
    if (k < e)     a0 = cv[k];
    if (k + 2 < e) a1 = cv[k + 2];
#if HAVE_DOT2
    float acc[8] = {};
    for (; k < e; k += 4) {
        uint2 c0 = a0, c1 = a1;
        bool ok1 = (k + 2) < e;
        int e1 = e - 1;
        a0 = cv[min(k + 4, e1)];
        a1 = cv[min(k + 6, e1)];
        unsigned col1 = ok1 ? c1.x : c0.x;
        float va1f = ok1 ? __uint_as_float(c1.y) : 0.f;
        unsigned vv = (unsigned)f2b(__uint_as_float(c0.y)) | ((unsigned)f2b(va1f) << 16);
        uint4 x0 = *(const uint4*)(X + (size_t)c0.x * NHID + l * 8);
        uint4 x1 = *(const uint4*)(X + (size_t)col1 * NHID + l * 8);
        acc[0] = dot2b(pack_lo(x0.x, x1.x), vv, acc[0]);
        acc[1] = dot2b(pack_hi(x0.x, x1.x), vv, acc[1]);
        acc[2] = dot2b(pack_lo(x0.y, x1.y), vv, acc[2]);
        acc[3] = dot2b(pack_hi(x0.y, x1.y), vv, acc[3]);
        acc[4] = dot2b(pack_lo(x0.z, x1.z), vv, acc[4]);
        acc[5] = dot2b(pack_hi(x0.z, x1.z), vv, acc[5]);
        acc[6] = dot2b(pack_lo(x0.w, x1.w), vv, acc[6]);
        acc[7] = dot2b(pack_hi(x0.w, x1.w), vv, acc[7]);
    }
    #pragma unroll
    for (int i = 0; i < 8; ++i) {
        float v = acc[i];
        v += __shfl_xor(v, 32);
        v += bias[l * 8 + i];
        acc[i] = RELU ? fmaxf(v, 0.f) : v;
    }
    float* accw = acc;
#else
    float acc0[8] = {}, acc1[8] = {};
    for (; k < e; k += 4) {
        uint2 c0 = a0, c1 = a1;
        bool ok1 = (k + 2) < e;
        int e1 = e - 1;
        a0 = cv[min(k + 4, e1)];
        a1 = cv[min(k + 6, e1)];
        float va0 = __uint_as_float(c0.y);
        float va1 = ok1 ? __uint_as_float(c1.y) : 0.f;
        unsigned col1 = ok1 ? c1.x : c0.x;
        u16x8 x0 = *(const u16x8*)(X + (size_t)c0.x * NHID + l * 8);
        u16x8 x1 = *(const u16x8*)(X + (size_t)col1 * NHID + l * 8);
        #pragma unroll
        for (int i = 0; i < 8; ++i) {
            acc0[i] = fmaf(va0, b2f(x0[i]), acc0[i]);
            acc1[i] = fmaf(va1, b2f(x1[i]), acc1[i]);
        }
    }
    #pragma unroll
    for (int i = 0; i < 8; ++i) {
        float v = acc0[i] + acc1[i];
        v += __shfl_xor(v, 32);
        v += bias[l * 8 + i];
        acc0[i] = RELU ? fmaxf(v, 0.f) : v;
    }
    float* accw = acc0;
#endif
    if (hw == 0) {
        u16x8 o;
        #pragma unroll
        for (int i = 0; i < 8; ++i) o[i] = f2b(accw[i]);
        *(u16x8*)(Out + ((size_t)tl * N_NODES + row) * NHID + l * 8) = o;
    }
}

// ---------------------------------------------------------------------------
// SpMM layer1 (D=128): quarter-wave per edge stream, 2 streams (r7 version).
// ---------------------------------------------------------------------------
template<bool RELU>
__global__ __launch_bounds__(256) void k_spmm1(
        const int* __restrict__ rp_all, const uint2* __restrict__ cv_all,
        int t0, const u16* __restrict__ X, size_t xtstride,
        const float* __restrict__ bias, u16* __restrict__ Out) {
    int lane = threadIdx.x & 63;
    int row = blockIdx.x * 4 + (threadIdx.x >> 6);
    int tl = blockIdx.y, t = t0 + tl;
    const int*   rp = rp_all + (size_t)t * (N_NODES + 1);
    const uint2* cv = cv_all + (size_t)t * E_EDGES;
    const u16*   Xt = X + xtstride * tl;
    int qw = lane >> 4, l = lane & 15;
    int s = rp[row], e = rp[row + 1];
    int k = s + qw;
    uint2 a0 = make_uint2(0u, 0u), a1 = make_uint2(0u, 0u);
    if (k < e)     a0 = cv[k];
    if (k + 4 < e) a1 = cv[k + 4];
#if HAVE_DOT2
    float acc[8] = {};
    for (; k < e; k += 8) {
        uint2 c0 = a0, c1 = a1;
        bool ok1 = (k + 4) < e;
        int e1 = e - 1;
        a0 = cv[min(k + 8, e1)];
        a1 = cv[min(k + 12, e1)];
        unsigned col1 = ok1 ? c1.x : c0.x;
        float va1f = ok1 ? __uint_as_float(c1.y) : 0.f;
        unsigned vv = (unsigned)f2b(__uint_as_float(c0.y)) | ((unsigned)f2b(va1f) << 16);
        uint4 x0 = *(const uint4*)(Xt + (size_t)c0.x * NOUT + l * 8);
        uint4 x1 = *(const uint4*)(Xt + (size_t)col1 * NOUT + l * 8);
        acc[0] = dot2b(pack_lo(x0.x, x1.x), vv, acc[0]);
        acc[1] = dot2b(pack_hi(x0.x, x1.x), vv, acc[1]);
        acc[2] = dot2b(pack_lo(x0.y, x1.y), vv, acc[2]);
        acc[3] = dot2b(pack_hi(x0.y, x1.y), vv, acc[3]);
        acc[4] = dot2b(pack_lo(x0.z, x1.z), vv, acc[4]);
        acc[5] = dot2b(pack_hi(x0.z, x1.z), vv, acc[5]);
        acc[6] = dot2b(pack_lo(x0.w, x1.w), vv, acc[6]);
        acc[7] = dot2b(pack_hi(x0.w, x1.w), vv, acc[7]);
    }
    #pragma unroll
    for (int i = 0; i < 8; ++i) {
        float v = acc[i];
        v += __shfl_xor(v, 32);
        v += __shfl_xor(v, 16);
        v += bias[l * 8 + i];
        acc[i] = RELU ? fmaxf(v, 0.f) : v;
    }
    float* accw = acc;
#else
    float acc0[8] = {}, acc1[8] = {};
    for (; k < e; k += 8) {
        uint2 c0 = a0, c1 = a1;
        bool ok1 = (k + 4) < e;
        int e1 = e - 1;
        a0 = cv[min(k + 8, e1)];
        a1 = cv[min(k + 12, e1)];
        float va0 = __uint_as_float(c0.y);
        float va1 = ok1 ? __uint_as_float(c1.y) : 0.f;
        unsigned col1 = ok1 ? c1.x : c0.x;
        u16x8 x0 = *(const u16x8*)(Xt + (size_t)c0.x * NOUT + l * 8);
        u16x8 x1 = *(const u16x8*)(Xt + (size_t)col1 * NOUT + l * 8);
        #pragma unroll
        for (int i = 0; i < 8; ++i) {
            acc0[i] = fmaf(va0, b2f(x0[i]), acc0[i]);
            acc1[i] = fmaf(va1, b2f(x1[i]), acc1[i]);
        }
    }
    #pragma unroll
    for (int i = 0; i < 8; ++i) {
        float v = acc0[i] + acc1[i];
        v += __shfl_xor(v, 32);
        v += __shfl_xor(v, 16);
        v += bias[l * 8 + i];
        acc0[i] = RELU ? fmaxf(v, 0.f) : v;
    }
    float* accw = acc0;
#endif
    if (qw == 0) {
        u16x8 o;
        #pragma unroll
        for (int i = 0; i < 8; ++i) o[i] = f2b(accw[i]);
        *(u16x8*)(Out + ((size_t)tl * N_NODES + row) * NOUT + l * 8) = o;
    }
}

// ---------------------------------------------------------------------------
// bf16 MFMA GEMM: C[M,Nc] = A[M,K] @ B^T (+bias), out bf16. tile 64x128.
// ---------------------------------------------------------------------------
template<int KC, bool BIAS>
__global__ __launch_bounds__(256) void k_mgemm(
        const u16* __restrict__ A, const u16* __restrict__ B, int ldb,
        const float* __restrict__ bias, u16* __restrict__ C, int ldc, int M) {
    constexpr int K = KC * 32;
    __shared__ bf16x8 frag[8 * KC * 64];
    int tid = threadIdx.x, lane = tid & 63, wave = tid >> 6;
    int m0 = blockIdx.y * 64, n0 = blockIdx.x * 128;

    for (int f = wave; f < 8 * KC; f += 4) {
        int nl = f / KC, kc = f % KC;
        frag[f * 64 + lane] = *(const bf16x8*)(B + (size_t)(n0 + nl * 16 + (lane & 15)) * ldb
                                               + kc * 32 + ((lane >> 4) << 3));
    }
    __syncthreads();

    int arow = m0 + wave * 16 + (lane & 15);
    bool rowok = arow < M;
    const u16* ap = A + (size_t)arow * K + ((lane >> 4) << 3);
    bf16x8 zf = {0, 0, 0, 0, 0, 0, 0, 0};
    bf16x8 af[KC];
    #pragma unroll
    for (int kc = 0; kc < KC; ++kc)
        af[kc] = rowok ? *(const bf16x8*)(ap + kc * 32) : zf;

    f32x4 acc[8] = {};
    #pragma unroll
    for (int kc = 0; kc < KC; ++kc)
        #pragma unroll
        for (int nl = 0; nl < 8; ++nl)
            acc[nl] = __builtin_amdgcn_mfma_f32_16x16x32_bf16(
                af[kc], frag[(nl * KC + kc) * 64 + lane], acc[nl], 0, 0, 0);

    int r0 = m0 + wave * 16 + ((lane >> 4) << 2);
    #pragma unroll
    for (int nl = 0; nl < 8; ++nl) {
        int col = n0 + nl * 16 + (lane & 15);
        float bv = BIAS ? bias[col] : 0.f;
        #pragma unroll
        for (int r = 0; r < 4; ++r) {
            int row = r0 + r;
            if (row < M) C[(size_t)row * ldc + col] = f2b(acc[nl][r] + bv);
        }
    }
}

// ---------------------------------------------------------------------------
// Fused all-16-step GRU: wave-specialized, Bg resident in VGPRs.
// Block = 16 nodes, 512 thr / 8 waves, 1250 blocks, launch_bounds(512,2),
// cross-barrier X2 prefetch (r16-proven).
// ---------------------------------------------------------------------------
__global__ __launch_bounds__(512, 2) void k_gru_fused2(
        const u16* __restrict__ X2_all, const u16* __restrict__ Bg,
        const float* __restrict__ bgb, float* __restrict__ H) {
    __shared__ u16 hbuf[2][16][132];           // 2 x 4.2 KB, +4 pad
    int tid = threadIdx.x, lane = tid & 63, wave = tid >> 6;
    int q = wave >> 1, hb = wave & 1;
    int u = lane & 15, kgrp = lane >> 4;       // kgrp 0..3
    int m0 = blockIdx.x * 16;
    int jj = (2 * q + hb) * 16 + u;            // this wave's hidden slice col

    // ---- load this wave's 32 B-fragments into registers (once) ----
    bf16x8 bfrag[4][8];
    #pragma unroll
    for (int g = 0; g < 4; ++g)
        #pragma unroll
        for (int kc = 0; kc < 8; ++kc)
            bfrag[g][kc] = *(const bf16x8*)(Bg
                + (size_t)(q * 128 + (4 * hb + g) * 16 + u) * 256
                + kc * 32 + kgrp * 8);

    float bR = bgb[q * 128 + (4 * hb + 0) * 16 + u];
    float bZ = bgb[q * 128 + (4 * hb + 1) * 16 + u];
    float bI = bgb[q * 128 + (4 * hb + 2) * 16 + u];
    float bH = bgb[q * 128 + (4 * hb + 3) * 16 + u];

    for (int i = tid; i < 16 * 132; i += 512) ((u16*)hbuf[0])[i] = 0;

    float hstate[4] = {};                      // [r] fp32 state
    int arow = m0 + u;
    const u16* aptr = X2_all + (size_t)arow * 128 + kgrp * 8;

    // prologue: preload step-0 x-fragments
    bf16x8 afx[4];
    #pragma unroll
    for (int kc = 0; kc < 4; ++kc)
        afx[kc] = *(const bf16x8*)(aptr + kc * 32);
    __syncthreads();

    for (int t = 0; t < T_SNAP; ++t) {
        int rb = t & 1, wb = rb ^ 1;
        bf16x8 afh[4];
        #pragma unroll
        for (int kc = 0; kc < 4; ++kc)
            afh[kc] = *(const bf16x8*)&hbuf[rb][u][kc * 32 + kgrp * 8];

        f32x4 acc[4] = {};
        #pragma unroll
        for (int kc = 0; kc < 4; ++kc)
            #pragma unroll
            for (int g = 0; g < 4; ++g)
                acc[g] = __builtin_amdgcn_mfma_f32_16x16x32_bf16(
                    afx[kc], bfrag[g][kc], acc[g], 0, 0, 0);
        #pragma unroll
        for (int kc = 0; kc < 4; ++kc)
            #pragma unroll
            for (int g = 0; g < 4; ++g)
                acc[g] = __builtin_amdgcn_mfma_f32_16x16x32_bf16(
                    afh[kc], bfrag[g][4 + kc], acc[g], 0, 0, 0);

        // prefetch next step's x-fragments (independent of h)
        bf16x8 afn[4];
        if (t + 1 < T_SNAP) {
            const u16* ap2 = aptr + (size_t)(t + 1) * N_NODES * 128;
            #pragma unroll
            for (int kc = 0; kc < 4; ++kc)
                afn[kc] = *(const bf16x8*)(ap2 + kc * 32);
        } else {
            #pragma unroll
            for (int kc = 0; kc < 4; ++kc) afn[kc] = afx[kc];
        }

        #pragma unroll
        for (int r = 0; r < 4; ++r) {
            int lrow = kgrp * 4 + r;
            float rg = fsig(acc[0][r] + bR);
            float zg = fsig(acc[1][r] + bZ);
            float ng = ftanh(acc[2][r] + bI + rg * (acc[3][r] + bH));
            float hn = (1.f - zg) * ng + zg * hstate[r];
            hstate[r] = hn;
            hbuf[wb][lrow][jj] = f2b(hn);
        }
        __syncthreads();   // wb complete before next step reads it
        #pragma unroll
        for (int kc = 0; kc < 4; ++kc) afx[kc] = afn[kc];
    }
    #pragma unroll
    for (int r = 0; r < 4; ++r) {
        int row = m0 + kgrp * 4 + r;
        H[(size_t)row * HDIM + jj] = hstate[r];
    }
}

// ---------------------------------------------------------------------------
// BatchNorm
// ---------------------------------------------------------------------------
__global__ void k_bnstats(const float* __restrict__ h, float* __restrict__ stats) {
    int j = threadIdx.x;
    int r0 = blockIdx.x * 200;
    float s = 0.f, sq = 0.f;
    for (int r = r0; r < r0 + 200; ++r) {
        float v = h[(size_t)r * HDIM + j];
        s += v; sq += v * v;
    }
    atomicAdd(&stats[j], s);
    atomicAdd(&stats[128 + j], sq);
}

__global__ void k_bnapply(const float* __restrict__ h, const float* __restrict__ stats,
                          const float* __restrict__ gamma, const float* __restrict__ beta,
                          u16* __restrict__ emb) {
    int i = blockIdx.x * 256 + threadIdx.x;
    if (i >= N_NODES * HDIM) return;
    int j = i & 127;
    float mean = stats[j] * (1.f / N_NODES);
    float var  = stats[128 + j] * (1.f / N_NODES) - mean * mean;
    emb[i] = f2b((h[i] - mean) * rsqrtf(var + BN_EPS) * gamma[j] + beta[j]);
}

// ---------------------------------------------------------------------------
// Edge predictor
// ---------------------------------------------------------------------------
__global__ __launch_bounds__(256) void k_edge(const int* __restrict__ edges,
        const u16* __restrict__ P, const u16* __restrict__ Q,
        const float* __restrict__ We2, const float* __restrict__ be2,
        float* __restrict__ out) {
    int e = blockIdx.x * 4 + (threadIdx.x >> 6);
    int lane = threadIdx.x & 63;
    if (e >= EP_EDGES) return;
    int u = edges[e];
    int v = edges[EP_EDGES + e];
    ushort4 pv = *(const ushort4*)(P + (size_t)u * NHID_E + lane * 4);
    ushort4 qv = *(const ushort4*)(Q + (size_t)v * NHID_E + lane * 4);
    const float4* w = (const float4*)(We2 + lane * 8);
    float4 w0 = w[0], w1 = w[1];
    float h0 = fmaxf(b2f(pv.x) + b2f(qv.x), 0.f);
    float h1 = fmaxf(b2f(pv.y) + b2f(qv.y), 0.f);
    float h2 = fmaxf(b2f(pv.z) + b2f(qv.z), 0.f);
    float h3 = fmaxf(b2f(pv.w) + b2f(qv.w), 0.f);
    float l0 = h0 * w0.x + h1 * w0.z + h2 * w1.x + h3 * w1.z;
    float l1 = h0 * w0.y + h1 * w0.w + h2 * w1.y + h3 * w1.w;
    #pragma unroll
    for (int off = 32; off > 0; off >>= 1) {
        l0 += __shfl_down(l0, off);
        l1 += __shfl_down(l1, off);
    }
    if (lane == 0) {
        l0 += be2[0]; l1 += be2[1];
        float m = fmaxf(l0, l1);
        float lse = m + logf(expf(l0 - m) + expf(l1 - m));
        out[(size_t)e * 2 + 0] = l0 - lse;
        out[(size_t)e * 2 + 1] = l1 - lse;
    }
}

// ---------------------------------------------------------------------------
extern "C" void kernel_launch(void* const* d_in, const int* in_sizes, int n_in,
                              void* d_out, int out_size, void* d_ws, size_t ws_size,
                              hipStream_t stream) {
    const int*   adj_rows = (const int*)  d_in[0];
    const int*   adj_cols = (const int*)  d_in[1];
    const float* adj_vals = (const float*)d_in[2];
    const int*   edges    = (const int*)  d_in[3];
    const float* W0   = (const float*)d_in[4];
    const float* b0   = (const float*)d_in[5];
    const float* W1   = (const float*)d_in[6];
    const float* b1   = (const float*)d_in[7];
    const float* W_ih = (const float*)d_in[8];
    const float* W_hh = (const float*)d_in[9];
    const float* b_ih = (const float*)d_in[10];
    const float* b_hh = (const float*)d_in[11];
    const float* gamma = (const float*)d_in[12];
    const float* beta  = (const float*)d_in[13];
    const float* We1  = (const float*)d_in[14];
    const float* be1  = (const float*)d_in[15];
    const float* We2  = (const float*)d_in[16];
    const float* be2  = (const float*)d_in[17];
    float* out = (float*)d_out;

    char* ws = (char*)d_ws;
    size_t off = 0;
    auto alloc = [&](size_t bytes) -> void* {
        void* p = ws + off;
        off += (bytes + 255) & ~(size_t)255;
        return p;
    };
    // ---- persistent ----
    int*   row_ptr = (int*)  alloc((size_t)T_SNAP * (N_NODES + 1) * 4);
    uint2* colval  = (uint2*)alloc((size_t)T_SNAP * E_EDGES * 8);
    u16*   W0_bf   = (u16*)  alloc((size_t)N_NODES * NHID * 2);
    u16*   W1t     = (u16*)  alloc((size_t)NOUT * NHID * 2);
    u16*   We1T    = (u16*)  alloc((size_t)NHID_E * 256 * 2);
    u16*   BgB     = (u16*)  alloc((size_t)512 * 256 * 2);
    float* bgbB    = (float*)alloc(512 * 4);
    float* h       = (float*)alloc((size_t)N_NODES * HDIM * 4);
    float* stats   = (float*)alloc(256 * 4);
    int*   bcnt    = (int*)  alloc((size_t)T_SNAP * NBUCK * 4);
    int*   bbase   = (int*)  alloc((size_t)T_SNAP * NBUCK * 4);
    int*   ovf_cnt = (int*)  alloc(256);
    size_t mark = off;

    // ---- union region: CSR phase ----
    off = mark;
    uint2* staging = (uint2*)alloc((size_t)T_SNAP * NBUCK * BCAP * 8);
    uint4* ovf     = (uint4*)alloc((size_t)T_SNAP * E_EDGES * 16);
    size_t csr_end = off;

    // ---- union region: compute phase (BT adaptive 16 -> 8 -> 4) ----
    int BT = 16;
    u16 *X0_b, *Y_b, *X2_all;
    size_t comp_end;
    for (;;) {
        off = mark;
        X0_b   = (u16*)alloc((size_t)BT * N_NODES * NHID * 2);
        Y_b    = (u16*)alloc((size_t)BT * N_NODES * NOUT * 2);
        X2_all = (u16*)alloc((size_t)T_SNAP * N_NODES * NOUT * 2);
        comp_end = off;
        if (comp_end <= ws_size || BT == 4) break;
        BT >>= 1;
    }

    // ---- union region: post phase ----
    off = mark;
    u16* emb = (u16*)alloc((size_t)N_NODES * HDIM * 2);
    u16* P   = (u16*)alloc((size_t)N_NODES * NHID_E * 2);
    u16* Q   = (u16*)alloc((size_t)N_NODES * NHID_E * 2);
    size_t post_end = off;

    size_t need = csr_end;
    if (comp_end > need) need = comp_end;
    if (post_end > need) need = post_end;
    if (need > ws_size) return;   // visible failure instead of corruption

    hipMemsetAsync(bcnt,    0, (size_t)T_SNAP * NBUCK * 4, stream);
    hipMemsetAsync(ovf_cnt, 0, 256, stream);
    hipMemsetAsync(stats,   0, 256 * 4, stream);

    // ---- CSR build v2 ----
    dim3 p1g((E_EDGES + P1CHUNK - 1) / P1CHUNK, T_SNAP);
    k_p1   <<<p1g, 256, 0, stream>>>(adj_rows, adj_cols, adj_vals, bcnt, staging, ovf, ovf_cnt);
    k_bscan<<<1, 256, 0, stream>>>(bcnt, bbase, row_ptr);
    k_p2   <<<dim3(NBUCK, T_SNAP), 256, 0, stream>>>(bcnt, bbase, staging, ovf, ovf_cnt,
                                                     colval, row_ptr);

    // ---- weight conversions ----
    k_cvt      <<<(N_NODES * NHID / 4 + 255) / 256, 256, 0, stream>>>(W0, W0_bf, N_NODES * NHID / 4);
    k_tcvt     <<<(NHID * NOUT + 255) / 256,  256, 0, stream>>>(W1, W1t, NHID, NOUT);
    k_tcvt     <<<(256 * NHID_E + 255) / 256, 256, 0, stream>>>(We1, We1T, 256, NHID_E);
    k_build_bg <<<(512 * 256 + 255) / 256, 256, 0, stream>>>(W_ih, W_hh, BgB);
    k_build_bgb<<<2, 256, 0, stream>>>(b_ih, b_hh, bgbB);

    // ---- batched GCN: layer0 spmm -> X0@W1 -> layer1 spmm -> X2_all ----
    for (int g = 0; g < T_SNAP; g += BT) {
        k_spmm0<true><<<dim3(N_NODES / 4, BT), 256, 0, stream>>>(
            row_ptr, colval, g, W0_bf, b0, X0_b);
        int M = BT * N_NODES;
        k_mgemm<8, false><<<dim3(1, (M + 63) / 64), 256, 0, stream>>>(
            X0_b, W1t, NHID, nullptr, Y_b, NOUT, M);
        k_spmm1<false><<<dim3(N_NODES / 4, BT), 256, 0, stream>>>(
            row_ptr, colval, g, Y_b, (size_t)N_NODES * NOUT, b1,
            X2_all + (size_t)g * N_NODES * NOUT);
    }

    // ---- GRU: all 16 steps fused, Bg in VGPRs, 1250 blocks (16 nodes each),
    //      cross-barrier X2 prefetch ----
    k_gru_fused2<<<N_NODES / 16, 512, 0, stream>>>(X2_all, BgB, bgbB, h);

    // ---- BatchNorm ----
    k_bnstats<<<100, 128, 0, stream>>>(h, stats);
    k_bnapply<<<(N_NODES * HDIM + 255) / 256, 256, 0, stream>>>(h, stats, gamma, beta, emb);

    // ---- Edge MLP precompute + predictor ----
    k_mgemm<4, true><<<dim3(2, (N_NODES + 63) / 64), 256, 0, stream>>>(
        emb, We1T, 256, be1, P, NHID_E, N_NODES);
    k_mgemm<4, false><<<dim3(2, (N_NODES + 63) / 64), 256, 0, stream>>>(
        emb, We1T + 128, 256, nullptr, Q, NHID_E, N_NODES);
    k_edge<<<(EP_EDGES + 3) / 4, 256, 0, stream>>>(edges, P, Q, We2, be2, out);
}